// Round 8
// baseline (614.104 us; speedup 1.0000x reference)
//
#include <hip/hip_runtime.h>
#include <math.h>

#define PAIRS 512
#define MAXN 192

// barrier with LDS ordering only — does NOT drain vmcnt, so global stores keep streaming
#define LDS_BAR() asm volatile("s_waitcnt lgkmcnt(0)\n\ts_barrier" ::: "memory")

// ---------------- offsets: exclusive prefix sums of len_s / len_t (shfl scan) ----------------
__global__ void offsets_kernel(const int* __restrict__ ls, const int* __restrict__ lt,
                               int* __restrict__ off) {
    __shared__ int wa[8], wb[8];
    int t = threadIdx.x;  // 512
    int a = ls[t], b = lt[t];
    int ia = a, ib = b;
#pragma unroll
    for (int d = 1; d < 64; d <<= 1) {
        int xa = __shfl_up(ia, d, 64);
        int xb = __shfl_up(ib, d, 64);
        if ((t & 63) >= d) { ia += xa; ib += xb; }
    }
    if ((t & 63) == 63) { wa[t >> 6] = ia; wb[t >> 6] = ib; }
    __syncthreads();
    int pa = 0, pb = 0;
    for (int w = 0; w < (t >> 6); w++) { pa += wa[w]; pb += wb[w]; }
    off[t] = pa + ia - a;          // exclusive
    off[PAIRS + t] = pb + ib - b;
}

// ================= CSR build over combined row space [0,Ns) ∪ [Ns,Ns+Nt) =================
__global__ __launch_bounds__(256) void count2_kernel(const int* __restrict__ eiS,
                                                     const int* __restrict__ eiT,
                                                     int* __restrict__ cnt,
                                                     int Es, int Et, int split) {
    int e = blockIdx.x * 256 + threadIdx.x;
    if (e < Es) atomicAdd(&cnt[eiS[Es + e]], 1);
    else if (e < Es + Et) atomicAdd(&cnt[split + eiT[Et + (e - Es)]], 1);
}

__global__ __launch_bounds__(256) void scan1_kernel(int* __restrict__ data,
                                                    int* __restrict__ blockSums, int N) {
    __shared__ int sc[256];
    int t = threadIdx.x;
    int base = blockIdx.x * 1024;
    int v[4];
    int s = 0;
#pragma unroll
    for (int q = 0; q < 4; q++) {
        int i = base + t * 4 + q;
        v[q] = (i < N) ? data[i] : 0;
        s += v[q];
    }
    sc[t] = s;
    __syncthreads();
    for (int d = 1; d < 256; d <<= 1) {
        int x = (t >= d) ? sc[t - d] : 0;
        __syncthreads();
        sc[t] += x;
        __syncthreads();
    }
    int excl = sc[t] - s;
#pragma unroll
    for (int q = 0; q < 4; q++) {
        int i = base + t * 4 + q;
        if (i < N) { data[i] = excl; excl += v[q]; }
    }
    if (t == 255) blockSums[blockIdx.x] = sc[255];
}

__global__ void scan2_kernel(int* __restrict__ blockSums, int B) {
    __shared__ int sh[256];
    int t = threadIdx.x;  // 256
    int v = (t < B) ? blockSums[t] : 0;
    sh[t] = v;
    __syncthreads();
    for (int d = 1; d < 256; d <<= 1) {
        int x = (t >= d) ? sh[t - d] : 0;
        __syncthreads();
        sh[t] += x;
        __syncthreads();
    }
    if (t < B) blockSums[t] = sh[t] - v;
}

__global__ __launch_bounds__(256) void scan3_kernel(int* __restrict__ data,
                                                    const int* __restrict__ blockSums,
                                                    int* __restrict__ cursor, int N) {
    int i = blockIdx.x * 256 + threadIdx.x;
    if (i < N) {
        int v = data[i] + blockSums[i >> 10];
        data[i] = v;
        cursor[i] = v;
    }
}

__global__ __launch_bounds__(256) void fill2_kernel(const int* __restrict__ eiS,
                                                    const int* __restrict__ eiT,
                                                    int* __restrict__ cursor,
                                                    int* __restrict__ src,
                                                    int Es, int Et, int split) {
    int e = blockIdx.x * 256 + threadIdx.x;
    if (e < Es) {
        int p = atomicAdd(&cursor[eiS[Es + e]], 1);
        src[p] = eiS[e];
    } else if (e < Es + Et) {
        int ee = e - Es;
        int p = atomicAdd(&cursor[split + eiT[Et + ee]], 1);
        src[p] = eiT[ee];
    }
}

// ================= gather aggregation (combined rows), float4-vectorized =================
template <int F>
__global__ __launch_bounds__(256) void gather_kernel(const float* __restrict__ featA,
                                                     const float* __restrict__ featB,
                                                     int split,
                                                     const int* __restrict__ rs,
                                                     const int* __restrict__ re,
                                                     const int* __restrict__ src,
                                                     float* __restrict__ agg, int N) {
    constexpr int F4 = F / 4;
    int gid = blockIdx.x * 256 + threadIdx.x;
    int row = gid / F4;
    int lane = threadIdx.x & (F4 - 1);
    if (row >= N) return;
    int b = rs[row], e = re[row];
    int cnt = e - b;
    const float* feat = (row < split) ? featA : featB;
    int pre = cnt < F4 ? cnt : F4;
    int sidx = (lane < cnt) ? src[b + lane] : 0;
    float4 acc = make_float4(0.f, 0.f, 0.f, 0.f);
    for (int q = 0; q < pre; q++) {
        int s = __shfl(sidx, q, F4);
        float4 v = ((const float4*)(feat + (size_t)s * F))[lane];
        acc.x += v.x; acc.y += v.y; acc.z += v.z; acc.w += v.w;
    }
    for (int q = b + F4; q < e; q++) {
        int s = src[q];
        float4 v = ((const float4*)(feat + (size_t)s * F))[lane];
        acc.x += v.x; acc.y += v.y; acc.z += v.z; acc.w += v.w;
    }
    ((float4*)(agg + (size_t)row * F))[lane] = acc;
}

// ========== register-tile GEMMs: 64 rows × 64 cols / block, 256 threads ==========
// thread map: i = tid&15 -> rows {i, i+16, i+32, i+48} ; j = tid>>4 -> cols 4j..4j+3
// A (and h2) row-major in LDS, stride 68 (float4-aligned; strided row ownership ->
//   A-read bank base (4i+4k4)%32: lanes i,i+8 pair = 2-way = free)

#define FMA_ROW(r, av)                                     \
    acc[r][0] = fmaf(av.x, w0.x, acc[r][0]);               \
    acc[r][1] = fmaf(av.x, w0.y, acc[r][1]);               \
    acc[r][2] = fmaf(av.x, w0.z, acc[r][2]);               \
    acc[r][3] = fmaf(av.x, w0.w, acc[r][3]);               \
    acc[r][0] = fmaf(av.y, w1.x, acc[r][0]);               \
    acc[r][1] = fmaf(av.y, w1.y, acc[r][1]);               \
    acc[r][2] = fmaf(av.y, w1.z, acc[r][2]);               \
    acc[r][3] = fmaf(av.y, w1.w, acc[r][3]);               \
    acc[r][0] = fmaf(av.z, w2.x, acc[r][0]);               \
    acc[r][1] = fmaf(av.z, w2.y, acc[r][1]);               \
    acc[r][2] = fmaf(av.z, w2.z, acc[r][2]);               \
    acc[r][3] = fmaf(av.z, w2.w, acc[r][3]);               \
    acc[r][0] = fmaf(av.w, w3.x, acc[r][0]);               \
    acc[r][1] = fmaf(av.w, w3.y, acc[r][1]);               \
    acc[r][2] = fmaf(av.w, w3.z, acc[r][2]);               \
    acc[r][3] = fmaf(av.w, w3.w, acc[r][3]);

#define GEMM_INNER(KW4, AKP, WBP)                                          \
    _Pragma("unroll") for (int k4 = 0; k4 < (KW4); k4++) {                 \
        float4 a0 = *(const float4*)((AKP) + (i)      * 68 + 4 * k4);      \
        float4 a1 = *(const float4*)((AKP) + (i + 16) * 68 + 4 * k4);      \
        float4 a2 = *(const float4*)((AKP) + (i + 32) * 68 + 4 * k4);      \
        float4 a3 = *(const float4*)((AKP) + (i + 48) * 68 + 4 * k4);      \
        float4 w0 = (WBP)[(4 * k4 + 0) * 16 + j];                          \
        float4 w1 = (WBP)[(4 * k4 + 1) * 16 + j];                          \
        float4 w2 = (WBP)[(4 * k4 + 2) * 16 + j];                          \
        float4 w3 = (WBP)[(4 * k4 + 3) * 16 + j];                          \
        FMA_ROW(0, a0) FMA_ROW(1, a1) FMA_ROW(2, a2) FMA_ROW(3, a3)        \
    }

// h_out = relu([agg | hin] @ [Wrel ; Wroot] + b)   (K' = 2*KIN, chunks of 64)
template <int KIN>
__global__ __launch_bounds__(256) void lin_gemm_kernel(const float* __restrict__ agg,
    const float* __restrict__ hinA, const float* __restrict__ hinB, int split,
    const float* __restrict__ Wrel, const float* __restrict__ brel,
    const float* __restrict__ Wroot, float* __restrict__ hout, int N) {
    __shared__ float Abuf[64 * 68];
    __shared__ float4 Wbuf[64 * 16];
    int tid = threadIdx.x;
    int i = tid & 15, j = tid >> 4;
    int rowbase = blockIdx.x * 64;
    float4 bv = ((const float4*)brel)[j];
    float acc[4][4];
#pragma unroll
    for (int r = 0; r < 4; r++) { acc[r][0] = bv.x; acc[r][1] = bv.y; acc[r][2] = bv.z; acc[r][3] = bv.w; }

    for (int c0 = 0; c0 < 2 * KIN; c0 += 64) {
        __syncthreads();
        for (int t = tid; t < 1024; t += 256) {
            int k4 = t & 15, r = t >> 4;
            int kg = c0 + 4 * k4;
            int row = rowbase + r; if (row >= N) row = N - 1;
            float4 v;
            if (kg < KIN) {
                v = ((const float4*)(agg + (size_t)row * KIN))[kg >> 2];
            } else {
                int kk = kg - KIN;
                const float* h = (row < split) ? hinA + (size_t)row * KIN
                                               : hinB + (size_t)(row - split) * KIN;
                v = ((const float4*)h)[kk >> 2];
            }
            *(float4*)(Abuf + r * 68 + 4 * k4) = v;
        }
        for (int t = tid; t < 1024; t += 256) {
            int k = t >> 4, jj = t & 15;
            int kg = c0 + k;
            const float* Wsrc = (kg < KIN) ? (Wrel + (size_t)kg * 64)
                                           : (Wroot + (size_t)(kg - KIN) * 64);
            Wbuf[t] = ((const float4*)Wsrc)[jj];
        }
        __syncthreads();
        GEMM_INNER(16, Abuf, Wbuf)
    }
#pragma unroll
    for (int r = 0; r < 4; r++) {
        int row = rowbase + i + 16 * r;
        if (row < N) {
            float4 o = make_float4(fmaxf(acc[r][0], 0.f), fmaxf(acc[r][1], 0.f),
                                   fmaxf(acc[r][2], 0.f), fmaxf(acc[r][3], 0.f));
            ((float4*)(hout + (size_t)row * 64))[j] = o;
        }
    }
}

// ===== FUSED layer2 + emb: h2 kept row-major in LDS; emb = normalize([x|h1|h2]@We+be) in-place =====
__global__ __launch_bounds__(256) void lin64_emb_kernel(
    const float* __restrict__ agg, const float* __restrict__ h1,
    const float* __restrict__ xA, const float* __restrict__ xB, int split,
    const float* __restrict__ Wrel, const float* __restrict__ brel,
    const float* __restrict__ Wroot,
    const float* __restrict__ We, const float* __restrict__ be,
    float* __restrict__ emb, int N) {
    __shared__ float Abuf[64 * 68];
    __shared__ float4 Wbuf[64 * 16];
    __shared__ float h2buf[64 * 68];   // row-major [row][k], stride 68
    int tid = threadIdx.x;
    int i = tid & 15, j = tid >> 4;
    int rowbase = blockIdx.x * 64;

    // ---------- phase A: h2 = relu([agg | h1] @ [Wrel;Wroot] + brel) ----------
    {
        float4 bv = ((const float4*)brel)[j];
        float acc[4][4];
#pragma unroll
        for (int r = 0; r < 4; r++) { acc[r][0] = bv.x; acc[r][1] = bv.y; acc[r][2] = bv.z; acc[r][3] = bv.w; }

        for (int c0 = 0; c0 < 128; c0 += 64) {
            __syncthreads();
            for (int t = tid; t < 1024; t += 256) {
                int k4 = t & 15, r = t >> 4;
                int kg = c0 + 4 * k4;
                int row = rowbase + r; if (row >= N) row = N - 1;
                float4 v;
                if (kg < 64) v = ((const float4*)(agg + (size_t)row * 64))[kg >> 2];
                else         v = ((const float4*)(h1 + (size_t)row * 64))[(kg - 64) >> 2];
                *(float4*)(Abuf + r * 68 + 4 * k4) = v;
            }
            for (int t = tid; t < 1024; t += 256) {
                int k = t >> 4, jj = t & 15;
                int kg = c0 + k;
                const float* Wsrc = (kg < 64) ? (Wrel + (size_t)kg * 64)
                                              : (Wroot + (size_t)(kg - 64) * 64);
                Wbuf[t] = ((const float4*)Wsrc)[jj];
            }
            __syncthreads();
            GEMM_INNER(16, Abuf, Wbuf)
        }
#pragma unroll
        for (int r = 0; r < 4; r++) {
            float4 o = make_float4(fmaxf(acc[r][0], 0.f), fmaxf(acc[r][1], 0.f),
                                   fmaxf(acc[r][2], 0.f), fmaxf(acc[r][3], 0.f));
            *(float4*)(h2buf + (i + 16 * r) * 68 + 4 * j) = o;
        }
    }

    // ---------- phase B: emb = normalize([x | h1 | h2] @ We + be) ----------
    float4 bv = ((const float4*)be)[j];
    float acc[4][4];
#pragma unroll
    for (int r = 0; r < 4; r++) { acc[r][0] = bv.x; acc[r][1] = bv.y; acc[r][2] = bv.z; acc[r][3] = bv.w; }

    // chunk 0: k in [0,64) from x|h1  (barrier also covers h2buf writes)
    __syncthreads();
    for (int t = tid; t < 1024; t += 256) {
        int k4 = t & 15, r = t >> 4;
        int kg = 4 * k4;
        int row = rowbase + r; if (row >= N) row = N - 1;
        float4 v;
        if (kg < 32) {
            const float* x = (row < split) ? xA + (size_t)row * 32
                                           : xB + (size_t)(row - split) * 32;
            v = ((const float4*)x)[kg >> 2];
        } else {
            v = ((const float4*)(h1 + (size_t)row * 64))[(kg - 32) >> 2];
        }
        *(float4*)(Abuf + r * 68 + 4 * k4) = v;
    }
    for (int t = tid; t < 1024; t += 256) {
        int k = t >> 4, jj = t & 15;
        Wbuf[t] = ((const float4*)(We + (size_t)k * 64))[jj];
    }
    __syncthreads();
    GEMM_INNER(16, Abuf, Wbuf)

    // chunk 1: k in [64,96) -> h1 cols 32..63 (kw = 32)
    __syncthreads();
    for (int t = tid; t < 512; t += 256) {
        int k4 = t & 7, r = t >> 3;
        int row = rowbase + r; if (row >= N) row = N - 1;
        float4 v = ((const float4*)(h1 + (size_t)row * 64))[8 + k4];
        *(float4*)(Abuf + r * 68 + 4 * k4) = v;
    }
    for (int t = tid; t < 512; t += 256) {
        int k = t >> 4, jj = t & 15;
        Wbuf[t] = ((const float4*)(We + (size_t)(64 + k) * 64))[jj];
    }
    __syncthreads();
    GEMM_INNER(8, Abuf, Wbuf)

    // chunk 2: k in [96,160) directly from h2buf (same conflict-free read pattern)
    __syncthreads();
    for (int t = tid; t < 1024; t += 256) {
        int k = t >> 4, jj = t & 15;
        Wbuf[t] = ((const float4*)(We + (size_t)(96 + k) * 64))[jj];
    }
    __syncthreads();
    GEMM_INNER(16, h2buf, Wbuf)

    // normalize epilogue
    __syncthreads();
#pragma unroll
    for (int r = 0; r < 4; r++)
#pragma unroll
        for (int c = 0; c < 4; c++)
            Abuf[(i + 16 * r) * 68 + 4 * j + c] = acc[r][c];
    __syncthreads();
    int lane = tid & 63, wv = tid >> 6;   // 4 waves, 16 rows each
    for (int rr = 0; rr < 16; rr++) {
        int r = wv * 16 + rr;
        float val = Abuf[r * 68 + lane];
        float ss = val * val;
#pragma unroll
        for (int d = 32; d > 0; d >>= 1) ss += __shfl_xor(ss, d, 64);
        int row = rowbase + r;
        if (row < N) emb[(size_t)row * 64 + lane] = val / fmaxf(sqrtf(ss), 1e-12f);
    }
}

// ================= FUSED cost + Sinkhorn: one block per pair, K in registers =================
__device__ __forceinline__ void dot_half(float kh[3][12], const float* sS, const float* sT,
                                         int ti, int tj) {
#pragma unroll
    for (int s = 0; s < 3; s++)
#pragma unroll
        for (int b = 0; b < 12; b++) kh[s][b] = 0.f;
    for (int k4 = 0; k4 < 16; k4++) {
        float4 a0 = *(const float4*)(sS + (3 * ti + 0) * 68 + 4 * k4);
        float4 a1 = *(const float4*)(sS + (3 * ti + 1) * 68 + 4 * k4);
        float4 a2 = *(const float4*)(sS + (3 * ti + 2) * 68 + 4 * k4);
#pragma unroll
        for (int b = 0; b < 12; b++) {
            float4 tb = *(const float4*)(sT + (12 * tj + b) * 68 + 4 * k4);
            kh[0][b] = fmaf(a0.x, tb.x, kh[0][b]);
            kh[0][b] = fmaf(a0.y, tb.y, kh[0][b]);
            kh[0][b] = fmaf(a0.z, tb.z, kh[0][b]);
            kh[0][b] = fmaf(a0.w, tb.w, kh[0][b]);
            kh[1][b] = fmaf(a1.x, tb.x, kh[1][b]);
            kh[1][b] = fmaf(a1.y, tb.y, kh[1][b]);
            kh[1][b] = fmaf(a1.z, tb.z, kh[1][b]);
            kh[1][b] = fmaf(a1.w, tb.w, kh[1][b]);
            kh[2][b] = fmaf(a2.x, tb.x, kh[2][b]);
            kh[2][b] = fmaf(a2.y, tb.y, kh[2][b]);
            kh[2][b] = fmaf(a2.z, tb.z, kh[2][b]);
            kh[2][b] = fmaf(a2.w, tb.w, kh[2][b]);
        }
    }
}

__device__ __forceinline__ void epi_half(float kh[3][12], const float* sqS, const float* sqT,
                                         int h, int ti, int tj, int n, int p,
                                         float* __restrict__ cost_out) {
#pragma unroll
    for (int s = 0; s < 3; s++) {
        int i = 96 * h + 3 * ti + s;
        bool rv = i < n;
        float sqi = sqS[3 * ti + s];
        float tmp[12];
#pragma unroll
        for (int b = 0; b < 12; b++) {
            int j = 12 * tj + b;
            float cd = sqrtf(fmaxf(sqi + sqT[j] - 2.f * kh[s][b], 1e-12f));
            float c = (rv && (j < n)) ? cd : ((!rv && (j >= n)) ? 0.f : 1000.f);
            tmp[b] = c;
            kh[s][b] = __expf(-10.f * c);
        }
        float* orow = cost_out + ((size_t)p * MAXN + i) * MAXN + 12 * tj;
#pragma unroll
        for (int q = 0; q < 3; q++)
            ((float4*)orow)[q] = make_float4(tmp[4 * q], tmp[4 * q + 1],
                                             tmp[4 * q + 2], tmp[4 * q + 3]);
    }
}

// analytic pad-column fill: this thread's 12 cols are all >= n, so
// K[i][j] = (i>=n) ? 1 : 0 and cost = (i>=n) ? 0 : 1000 — no dot/exp needed.
__device__ __forceinline__ void pad_half(float kh[3][12], int h, int ti, int tj, int n,
                                         int p, float* __restrict__ cost_out) {
#pragma unroll
    for (int s = 0; s < 3; s++) {
        int i = 96 * h + 3 * ti + s;
        bool rpad = i >= n;
        float kv = rpad ? 1.f : 0.f;
        float cv = rpad ? 0.f : 1000.f;
#pragma unroll
        for (int b = 0; b < 12; b++) kh[s][b] = kv;
        float* orow = cost_out + ((size_t)p * MAXN + i) * MAXN + 12 * tj;
        float4 c4 = make_float4(cv, cv, cv, cv);
#pragma unroll
        for (int q = 0; q < 3; q++) ((float4*)orow)[q] = c4;
    }
}

// 512 threads: ti = tid&31 owns rows {96h + 3ti + s}, tj = tid>>5 owns cols {12tj + b}
// LDS: sT[192][68] + sS[96][68] + sq + virt ~ 79.7 KB -> 2 blocks/CU.
// All barriers after the first global store are LDS-only (stores stream in background).
// Pad columns (j >= n) are analytic (K block-diagonal) -> waves owning only pad
// columns skip the whole dot/exp path.
__global__ __launch_bounds__(512, 4) void fused_cost_sinkhorn_kernel(
    const float* __restrict__ embS, const float* __restrict__ embT,
    const float* __restrict__ vraw,
    const int* __restrict__ lenS, const int* __restrict__ lenT,
    const int* __restrict__ off,
    float* __restrict__ cost_out, float* __restrict__ gamma_out,
    float* __restrict__ geds2, int Ns) {
    __shared__ __align__(16) float sT[192 * 68];
    __shared__ __align__(16) float sS[96 * 68];
    __shared__ __align__(16) float sqT[192];
    __shared__ __align__(16) float sqS[96];
    __shared__ __align__(16) float virtv[64];

    int p = blockIdx.x;
    int tid = threadIdx.x;           // 512
    int ti = tid & 31;
    int tj = tid >> 5;               // 0..15
    int n = lenS[p], m = lenT[p];
    int offs = off[p], offt = off[PAIRS + p];
    bool skipw = (12 * tj >= n);     // all 12 owned columns are pad

    if (tid < 64) {
        float v = vraw[tid];
        float ss = v * v;
#pragma unroll
        for (int d = 32; d > 0; d >>= 1) ss += __shfl_xor(ss, d, 64);
        virtv[tid] = v / fmaxf(sqrtf(ss), 1e-12f);
    }
    __syncthreads();

    // stage T-augmented rows + S half 0
    for (int t = tid; t < 192 * 16; t += 512) {
        int j = t >> 4, q = t & 15;
        float4 vv = (j < m) ? ((const float4*)embT)[(size_t)(offt + j) * 16 + q]
                            : ((const float4*)virtv)[q];
        *(float4*)(sT + j * 68 + 4 * q) = vv;
    }
    for (int t = tid; t < 96 * 16; t += 512) {
        int r = t >> 4, q = t & 15;
        int gi = offs + r; if (gi > Ns - 1) gi = Ns - 1;
        float4 vv = ((const float4*)embS)[(size_t)gi * 16 + q];
        *(float4*)(sS + r * 68 + 4 * q) = vv;
    }
    __syncthreads();
    if (tid < 192) {
        float s = 0.f;
#pragma unroll
        for (int k = 0; k < 64; k++) { float a = sT[tid * 68 + k]; s = fmaf(a, a, s); }
        sqT[tid] = s;
    } else if (tid < 288) {
        int r = tid - 192;
        float s = 0.f;
#pragma unroll
        for (int k = 0; k < 64; k++) { float a = sS[r * 68 + k]; s = fmaf(a, a, s); }
        sqS[r] = s;
    }
    __syncthreads();

    float kf[2][3][12];

    // ---- half 0: dot (real cols only), then prefetch S-half1 to regs ----
    if (!skipw) dot_half(kf[0], sS, sT, ti, tj);
    float4 pf0, pf1, pf2;
    {
        int t0 = tid, t1 = tid + 512, t2 = tid + 1024;
        int gi0 = offs + 96 + (t0 >> 4); if (gi0 > Ns - 1) gi0 = Ns - 1;
        int gi1 = offs + 96 + (t1 >> 4); if (gi1 > Ns - 1) gi1 = Ns - 1;
        int gi2 = offs + 96 + (t2 >> 4); if (gi2 > Ns - 1) gi2 = Ns - 1;
        pf0 = ((const float4*)embS)[(size_t)gi0 * 16 + (t0 & 15)];
        pf1 = ((const float4*)embS)[(size_t)gi1 * 16 + (t1 & 15)];
        pf2 = ((const float4*)embS)[(size_t)gi2 * 16 + (t2 & 15)];
    }
    if (!skipw) epi_half(kf[0], sqS, sqT, 0, ti, tj, n, p, cost_out);  // issues cost stores
    else        pad_half(kf[0], 0, ti, tj, n, p, cost_out);

    LDS_BAR();   // dot/epilogue LDS reads done; stores NOT drained
    {
        int t0 = tid, t1 = tid + 512, t2 = tid + 1024;
        *(float4*)(sS + (t0 >> 4) * 68 + 4 * (t0 & 15)) = pf0;
        *(float4*)(sS + (t1 >> 4) * 68 + 4 * (t1 & 15)) = pf1;
        *(float4*)(sS + (t2 >> 4) * 68 + 4 * (t2 & 15)) = pf2;
    }
    LDS_BAR();
    if (tid < 96) {
        float s = 0.f;
#pragma unroll
        for (int k = 0; k < 64; k++) { float a = sS[tid * 68 + k]; s = fmaf(a, a, s); }
        sqS[tid] = s;
    }
    LDS_BAR();

    // ---- half 1 ----
    if (!skipw) {
        dot_half(kf[1], sS, sT, ti, tj);
        epi_half(kf[1], sqS, sqT, 1, ti, tj, n, p, cost_out);
    } else {
        pad_half(kf[1], 1, ti, tj, n, p, cost_out);
    }
    LDS_BAR();   // emb tiles dead; alias scratch over sS / sqT

    float* part = sS;          // partV: [192][33] (6336 f) / partU: [16][192] (3072 f)
    float* ubuf = sS + 6336;   // 192 floats
    float* vbuf = sqT;         // 192 floats

    if (tid < 192) ubuf[tid] = 1.f / 192.f;
    LDS_BAR();

    for (int it = 0; it < 8; it++) {
        // ---- v = 1 / (K^T u) ----
        float uloc[6];
#pragma unroll
        for (int h = 0; h < 2; h++)
#pragma unroll
            for (int s = 0; s < 3; s++) uloc[3 * h + s] = ubuf[96 * h + 3 * ti + s];
#pragma unroll
        for (int b = 0; b < 12; b++) {
            float a = 0.f;
#pragma unroll
            for (int h = 0; h < 2; h++)
#pragma unroll
                for (int s = 0; s < 3; s++) a = fmaf(kf[h][s][b], uloc[3 * h + s], a);
            part[(12 * tj + b) * 33 + ti] = a;
        }
        LDS_BAR();
        if (tid < 192) {
            float s = 0.f;
#pragma unroll
            for (int g = 0; g < 32; g++) s += part[tid * 33 + g];
            vbuf[tid] = 1.f / s;
        }
        LDS_BAR();
        // ---- u = 1 / (K v) ----
        float vloc[12];
        {
            float4 va = *(const float4*)(vbuf + 12 * tj);
            float4 vb = *(const float4*)(vbuf + 12 * tj + 4);
            float4 vc = *(const float4*)(vbuf + 12 * tj + 8);
            vloc[0] = va.x; vloc[1] = va.y; vloc[2] = va.z; vloc[3] = va.w;
            vloc[4] = vb.x; vloc[5] = vb.y; vloc[6] = vb.z; vloc[7] = vb.w;
            vloc[8] = vc.x; vloc[9] = vc.y; vloc[10] = vc.z; vloc[11] = vc.w;
        }
#pragma unroll
        for (int h = 0; h < 2; h++)
#pragma unroll
            for (int s = 0; s < 3; s++) {
                float a = 0.f;
#pragma unroll
                for (int b = 0; b < 12; b++) a = fmaf(kf[h][s][b], vloc[b], a);
                part[tj * 192 + 96 * h + 3 * ti + s] = a;
            }
        LDS_BAR();
        if (tid < 192) {
            float s = 0.f;
#pragma unroll
            for (int g = 0; g < 16; g++) s += part[g * 192 + tid];
            ubuf[tid] = 1.f / s;
        }
        LDS_BAR();
    }

    // ---- gamma = u .* K .* v, geds2 = sum(gamma * cost) / (n + m) ----
    float vloc[12];
    {
        float4 va = *(const float4*)(vbuf + 12 * tj);
        float4 vb = *(const float4*)(vbuf + 12 * tj + 4);
        float4 vc = *(const float4*)(vbuf + 12 * tj + 8);
        vloc[0] = va.x; vloc[1] = va.y; vloc[2] = va.z; vloc[3] = va.w;
        vloc[4] = vb.x; vloc[5] = vb.y; vloc[6] = vb.z; vloc[7] = vb.w;
        vloc[8] = vc.x; vloc[9] = vc.y; vloc[10] = vc.z; vloc[11] = vc.w;
    }
    float accg = 0.f;
    if (!skipw) {
#pragma unroll
        for (int h = 0; h < 2; h++)
#pragma unroll
            for (int s = 0; s < 3; s++) {
                int i = 96 * h + 3 * ti + s;
                float ui = ubuf[i];
                float tmp[12];
#pragma unroll
                for (int b = 0; b < 12; b++) {
                    float Kij = kf[h][s][b];
                    float gg = ui * Kij * vloc[b];
                    tmp[b] = gg;
                    if (Kij > 0.f) accg = fmaf(gg, -0.1f * __logf(Kij), accg);
                }
                float* grow = gamma_out + ((size_t)p * MAXN + i) * MAXN + 12 * tj;
#pragma unroll
                for (int q = 0; q < 3; q++)
                    ((float4*)grow)[q] = make_float4(tmp[4 * q], tmp[4 * q + 1],
                                                     tmp[4 * q + 2], tmp[4 * q + 3]);
            }
    } else {
        // pad columns: K uniform per row (0 or 1); cost contribution is exactly 0
#pragma unroll
        for (int h = 0; h < 2; h++)
#pragma unroll
            for (int s = 0; s < 3; s++) {
                int i = 96 * h + 3 * ti + s;
                float g0 = (i >= n) ? ubuf[i] : 0.f;   // ui * kv
                float tmp[12];
#pragma unroll
                for (int b = 0; b < 12; b++) tmp[b] = g0 * vloc[b];
                float* grow = gamma_out + ((size_t)p * MAXN + i) * MAXN + 12 * tj;
#pragma unroll
                for (int q = 0; q < 3; q++)
                    ((float4*)grow)[q] = make_float4(tmp[4 * q], tmp[4 * q + 1],
                                                     tmp[4 * q + 2], tmp[4 * q + 3]);
            }
    }
#pragma unroll
    for (int d = 32; d > 0; d >>= 1) accg += __shfl_xor(accg, d, 64);
    if ((tid & 63) == 0) sqS[tid >> 6] = accg;
    LDS_BAR();
    if (tid == 0) {
        float s = 0.f;
        for (int w = 0; w < 8; w++) s += sqS[w];
        geds2[p] = s / (float)(n + m);
    }
}

extern "C" void kernel_launch(void* const* d_in, const int* in_sizes, int n_in,
                              void* d_out, int out_size, void* d_ws, size_t ws_size,
                              hipStream_t stream) {
    const float* x_s     = (const float*)d_in[0];
    const float* x_t     = (const float*)d_in[1];
    const float* W_rel0  = (const float*)d_in[2];
    const float* b_rel0  = (const float*)d_in[3];
    const float* W_root0 = (const float*)d_in[4];
    const float* W_rel1  = (const float*)d_in[5];
    const float* b_rel1  = (const float*)d_in[6];
    const float* W_root1 = (const float*)d_in[7];
    const float* W_e     = (const float*)d_in[8];
    const float* b_e     = (const float*)d_in[9];
    const float* virt    = (const float*)d_in[10];
    const int*   ei_s    = (const int*)d_in[11];
    const int*   ei_t    = (const int*)d_in[12];
    const int*   len_s   = (const int*)d_in[13];
    const int*   len_t   = (const int*)d_in[14];

    int Ns = in_sizes[0] / 32;
    int Nt = in_sizes[1] / 32;
    int Es = in_sizes[11] / 2;
    int Et = in_sizes[12] / 2;
    int Ntot = Ns + Nt;
    int Etot = Es + Et;

    // ---- workspace layout ----
    char* w = (char*)d_ws;
    int* off  = (int*)w;              w += 1024 * 4;
    int* bsum = (int*)w;              w += 256 * 4;
    int* rs   = (int*)w;              w += (size_t)Ntot * 4;
    int* cur  = (int*)w;              w += (size_t)Ntot * 4;
    int* src  = (int*)w;              w += (size_t)Etot * 4;
    w = (char*)(((size_t)w + 255) & ~(size_t)255);
    float* agg = (float*)w;           w += (size_t)Ntot * 64 * 4;  // gather out; later emb (in-place)
    float* h1  = (float*)w;           w += (size_t)Ntot * 64 * 4;

    float* out_gamma = (float*)d_out;
    float* out_cost  = out_gamma + (size_t)PAIRS * MAXN * MAXN;
    float* out_geds  = out_cost + (size_t)PAIRS * MAXN * MAXN;

    offsets_kernel<<<1, PAIRS, 0, stream>>>(len_s, len_t, off);

    // ---- combined CSR build ----
    hipMemsetAsync(rs, 0, (size_t)Ntot * 4, stream);
    count2_kernel<<<(Etot + 255) / 256, 256, 0, stream>>>(ei_s, ei_t, rs, Es, Et, Ns);
    int nb = (Ntot + 1023) / 1024;
    scan1_kernel<<<nb, 256, 0, stream>>>(rs, bsum, Ntot);
    scan2_kernel<<<1, 256, 0, stream>>>(bsum, nb);
    scan3_kernel<<<(Ntot + 255) / 256, 256, 0, stream>>>(rs, bsum, cur, Ntot);
    fill2_kernel<<<(Etot + 255) / 256, 256, 0, stream>>>(ei_s, ei_t, cur, src, Es, Et, Ns);

    int gblk = (Ntot + 63) / 64;

    // ---- combined GNN ----
    gather_kernel<32><<<(int)(((long long)Ntot * 8 + 255) / 256), 256, 0, stream>>>(
        x_s, x_t, Ns, rs, cur, src, agg, Ntot);
    lin_gemm_kernel<32><<<gblk, 256, 0, stream>>>(
        agg, x_s, x_t, Ns, W_rel0, b_rel0, W_root0, h1, Ntot);
    gather_kernel<64><<<(int)(((long long)Ntot * 16 + 255) / 256), 256, 0, stream>>>(
        h1, h1, Ns, rs, cur, src, agg, Ntot);
    // fused layer2 + emb: reads agg (own rows) + h1 + x, writes emb in-place into agg
    lin64_emb_kernel<<<gblk, 256, 0, stream>>>(
        agg, h1, x_s, x_t, Ns, W_rel1, b_rel1, W_root1, W_e, b_e, agg, Ntot);

    // ---- fused cost + sinkhorn ----
    fused_cost_sinkhorn_kernel<<<PAIRS, 512, 0, stream>>>(
        agg, agg + (size_t)Ns * 64, virt, len_s, len_t, off,
        out_cost, out_gamma, out_geds, Ns);
}

// Round 9
// 592.976 us; speedup vs baseline: 1.0356x; 1.0356x over previous
//
#include <hip/hip_runtime.h>
#include <math.h>

#define PAIRS 512
#define MAXN 192

// barrier with LDS ordering only — does NOT drain vmcnt, so global stores keep streaming
#define LDS_BAR() asm volatile("s_waitcnt lgkmcnt(0)\n\ts_barrier" ::: "memory")

// ---------------- offsets: exclusive prefix sums of len_s / len_t (shfl scan) ----------------
__global__ void offsets_kernel(const int* __restrict__ ls, const int* __restrict__ lt,
                               int* __restrict__ off) {
    __shared__ int wa[8], wb[8];
    int t = threadIdx.x;  // 512
    int a = ls[t], b = lt[t];
    int ia = a, ib = b;
#pragma unroll
    for (int d = 1; d < 64; d <<= 1) {
        int xa = __shfl_up(ia, d, 64);
        int xb = __shfl_up(ib, d, 64);
        if ((t & 63) >= d) { ia += xa; ib += xb; }
    }
    if ((t & 63) == 63) { wa[t >> 6] = ia; wb[t >> 6] = ib; }
    __syncthreads();
    int pa = 0, pb = 0;
    for (int w = 0; w < (t >> 6); w++) { pa += wa[w]; pb += wb[w]; }
    off[t] = pa + ia - a;          // exclusive
    off[PAIRS + t] = pb + ib - b;
}

// ================= CSR build over combined row space [0,Ns) ∪ [Ns,Ns+Nt) =================
__global__ __launch_bounds__(256) void count2_kernel(const int* __restrict__ eiS,
                                                     const int* __restrict__ eiT,
                                                     int* __restrict__ cnt,
                                                     int Es, int Et, int split) {
    int e = blockIdx.x * 256 + threadIdx.x;
    if (e < Es) atomicAdd(&cnt[eiS[Es + e]], 1);
    else if (e < Es + Et) atomicAdd(&cnt[split + eiT[Et + (e - Es)]], 1);
}

__global__ __launch_bounds__(256) void scan1_kernel(int* __restrict__ data,
                                                    int* __restrict__ blockSums, int N) {
    __shared__ int sc[256];
    int t = threadIdx.x;
    int base = blockIdx.x * 1024;
    int v[4];
    int s = 0;
#pragma unroll
    for (int q = 0; q < 4; q++) {
        int i = base + t * 4 + q;
        v[q] = (i < N) ? data[i] : 0;
        s += v[q];
    }
    sc[t] = s;
    __syncthreads();
    for (int d = 1; d < 256; d <<= 1) {
        int x = (t >= d) ? sc[t - d] : 0;
        __syncthreads();
        sc[t] += x;
        __syncthreads();
    }
    int excl = sc[t] - s;
#pragma unroll
    for (int q = 0; q < 4; q++) {
        int i = base + t * 4 + q;
        if (i < N) { data[i] = excl; excl += v[q]; }
    }
    if (t == 255) blockSums[blockIdx.x] = sc[255];
}

__global__ void scan2_kernel(int* __restrict__ blockSums, int B) {
    __shared__ int sh[256];
    int t = threadIdx.x;  // 256
    int v = (t < B) ? blockSums[t] : 0;
    sh[t] = v;
    __syncthreads();
    for (int d = 1; d < 256; d <<= 1) {
        int x = (t >= d) ? sh[t - d] : 0;
        __syncthreads();
        sh[t] += x;
        __syncthreads();
    }
    if (t < B) blockSums[t] = sh[t] - v;
}

__global__ __launch_bounds__(256) void scan3_kernel(int* __restrict__ data,
                                                    const int* __restrict__ blockSums,
                                                    int* __restrict__ cursor, int N) {
    int i = blockIdx.x * 256 + threadIdx.x;
    if (i < N) {
        int v = data[i] + blockSums[i >> 10];
        data[i] = v;
        cursor[i] = v;
    }
}

__global__ __launch_bounds__(256) void fill2_kernel(const int* __restrict__ eiS,
                                                    const int* __restrict__ eiT,
                                                    int* __restrict__ cursor,
                                                    int* __restrict__ src,
                                                    int Es, int Et, int split) {
    int e = blockIdx.x * 256 + threadIdx.x;
    if (e < Es) {
        int p = atomicAdd(&cursor[eiS[Es + e]], 1);
        src[p] = eiS[e];
    } else if (e < Es + Et) {
        int ee = e - Es;
        int p = atomicAdd(&cursor[split + eiT[Et + ee]], 1);
        src[p] = eiT[ee];
    }
}

// ================= gather aggregation (combined rows), float4-vectorized =================
template <int F>
__global__ __launch_bounds__(256) void gather_kernel(const float* __restrict__ featA,
                                                     const float* __restrict__ featB,
                                                     int split,
                                                     const int* __restrict__ rs,
                                                     const int* __restrict__ re,
                                                     const int* __restrict__ src,
                                                     float* __restrict__ agg, int N) {
    constexpr int F4 = F / 4;
    int gid = blockIdx.x * 256 + threadIdx.x;
    int row = gid / F4;
    int lane = threadIdx.x & (F4 - 1);
    if (row >= N) return;
    int b = rs[row], e = re[row];
    int cnt = e - b;
    const float* feat = (row < split) ? featA : featB;
    int pre = cnt < F4 ? cnt : F4;
    int sidx = (lane < cnt) ? src[b + lane] : 0;
    float4 acc = make_float4(0.f, 0.f, 0.f, 0.f);
    for (int q = 0; q < pre; q++) {
        int s = __shfl(sidx, q, F4);
        float4 v = ((const float4*)(feat + (size_t)s * F))[lane];
        acc.x += v.x; acc.y += v.y; acc.z += v.z; acc.w += v.w;
    }
    for (int q = b + F4; q < e; q++) {
        int s = src[q];
        float4 v = ((const float4*)(feat + (size_t)s * F))[lane];
        acc.x += v.x; acc.y += v.y; acc.z += v.z; acc.w += v.w;
    }
    ((float4*)(agg + (size_t)row * F))[lane] = acc;
}

// ========== register-tile GEMMs: 64 rows × 64 cols / block, 256 threads ==========
// thread map: i = tid&15 -> rows {i, i+16, i+32, i+48} ; j = tid>>4 -> cols 4j..4j+3
// A (and h2) row-major in LDS, stride 68 (float4-aligned; strided row ownership ->
//   A-read bank base (4i+4k4)%32: lanes i,i+8 pair = 2-way = free)

#define FMA_ROW(r, av)                                     \
    acc[r][0] = fmaf(av.x, w0.x, acc[r][0]);               \
    acc[r][1] = fmaf(av.x, w0.y, acc[r][1]);               \
    acc[r][2] = fmaf(av.x, w0.z, acc[r][2]);               \
    acc[r][3] = fmaf(av.x, w0.w, acc[r][3]);               \
    acc[r][0] = fmaf(av.y, w1.x, acc[r][0]);               \
    acc[r][1] = fmaf(av.y, w1.y, acc[r][1]);               \
    acc[r][2] = fmaf(av.y, w1.z, acc[r][2]);               \
    acc[r][3] = fmaf(av.y, w1.w, acc[r][3]);               \
    acc[r][0] = fmaf(av.z, w2.x, acc[r][0]);               \
    acc[r][1] = fmaf(av.z, w2.y, acc[r][1]);               \
    acc[r][2] = fmaf(av.z, w2.z, acc[r][2]);               \
    acc[r][3] = fmaf(av.z, w2.w, acc[r][3]);               \
    acc[r][0] = fmaf(av.w, w3.x, acc[r][0]);               \
    acc[r][1] = fmaf(av.w, w3.y, acc[r][1]);               \
    acc[r][2] = fmaf(av.w, w3.z, acc[r][2]);               \
    acc[r][3] = fmaf(av.w, w3.w, acc[r][3]);

#define GEMM_INNER(KW4, AKP, WBP)                                          \
    _Pragma("unroll") for (int k4 = 0; k4 < (KW4); k4++) {                 \
        float4 a0 = *(const float4*)((AKP) + (i)      * 68 + 4 * k4);      \
        float4 a1 = *(const float4*)((AKP) + (i + 16) * 68 + 4 * k4);      \
        float4 a2 = *(const float4*)((AKP) + (i + 32) * 68 + 4 * k4);      \
        float4 a3 = *(const float4*)((AKP) + (i + 48) * 68 + 4 * k4);      \
        float4 w0 = (WBP)[(4 * k4 + 0) * 16 + j];                          \
        float4 w1 = (WBP)[(4 * k4 + 1) * 16 + j];                          \
        float4 w2 = (WBP)[(4 * k4 + 2) * 16 + j];                          \
        float4 w3 = (WBP)[(4 * k4 + 3) * 16 + j];                          \
        FMA_ROW(0, a0) FMA_ROW(1, a1) FMA_ROW(2, a2) FMA_ROW(3, a3)        \
    }

// h_out = relu([agg | hin] @ [Wrel ; Wroot] + b)   (K' = 2*KIN, chunks of 64)
template <int KIN>
__global__ __launch_bounds__(256) void lin_gemm_kernel(const float* __restrict__ agg,
    const float* __restrict__ hinA, const float* __restrict__ hinB, int split,
    const float* __restrict__ Wrel, const float* __restrict__ brel,
    const float* __restrict__ Wroot, float* __restrict__ hout, int N) {
    __shared__ float Abuf[64 * 68];
    __shared__ float4 Wbuf[64 * 16];
    int tid = threadIdx.x;
    int i = tid & 15, j = tid >> 4;
    int rowbase = blockIdx.x * 64;
    float4 bv = ((const float4*)brel)[j];
    float acc[4][4];
#pragma unroll
    for (int r = 0; r < 4; r++) { acc[r][0] = bv.x; acc[r][1] = bv.y; acc[r][2] = bv.z; acc[r][3] = bv.w; }

    for (int c0 = 0; c0 < 2 * KIN; c0 += 64) {
        __syncthreads();
        for (int t = tid; t < 1024; t += 256) {
            int k4 = t & 15, r = t >> 4;
            int kg = c0 + 4 * k4;
            int row = rowbase + r; if (row >= N) row = N - 1;
            float4 v;
            if (kg < KIN) {
                v = ((const float4*)(agg + (size_t)row * KIN))[kg >> 2];
            } else {
                int kk = kg - KIN;
                const float* h = (row < split) ? hinA + (size_t)row * KIN
                                               : hinB + (size_t)(row - split) * KIN;
                v = ((const float4*)h)[kk >> 2];
            }
            *(float4*)(Abuf + r * 68 + 4 * k4) = v;
        }
        for (int t = tid; t < 1024; t += 256) {
            int k = t >> 4, jj = t & 15;
            int kg = c0 + k;
            const float* Wsrc = (kg < KIN) ? (Wrel + (size_t)kg * 64)
                                           : (Wroot + (size_t)(kg - KIN) * 64);
            Wbuf[t] = ((const float4*)Wsrc)[jj];
        }
        __syncthreads();
        GEMM_INNER(16, Abuf, Wbuf)
    }
#pragma unroll
    for (int r = 0; r < 4; r++) {
        int row = rowbase + i + 16 * r;
        if (row < N) {
            float4 o = make_float4(fmaxf(acc[r][0], 0.f), fmaxf(acc[r][1], 0.f),
                                   fmaxf(acc[r][2], 0.f), fmaxf(acc[r][3], 0.f));
            ((float4*)(hout + (size_t)row * 64))[j] = o;
        }
    }
}

// ===== FUSED layer2 + emb: h2 kept row-major in LDS; emb = normalize([x|h1|h2]@We+be) in-place =====
__global__ __launch_bounds__(256) void lin64_emb_kernel(
    const float* __restrict__ agg, const float* __restrict__ h1,
    const float* __restrict__ xA, const float* __restrict__ xB, int split,
    const float* __restrict__ Wrel, const float* __restrict__ brel,
    const float* __restrict__ Wroot,
    const float* __restrict__ We, const float* __restrict__ be,
    float* __restrict__ emb, int N) {
    __shared__ float Abuf[64 * 68];
    __shared__ float4 Wbuf[64 * 16];
    __shared__ float h2buf[64 * 68];   // row-major [row][k], stride 68
    int tid = threadIdx.x;
    int i = tid & 15, j = tid >> 4;
    int rowbase = blockIdx.x * 64;

    // ---------- phase A: h2 = relu([agg | h1] @ [Wrel;Wroot] + brel) ----------
    {
        float4 bv = ((const float4*)brel)[j];
        float acc[4][4];
#pragma unroll
        for (int r = 0; r < 4; r++) { acc[r][0] = bv.x; acc[r][1] = bv.y; acc[r][2] = bv.z; acc[r][3] = bv.w; }

        for (int c0 = 0; c0 < 128; c0 += 64) {
            __syncthreads();
            for (int t = tid; t < 1024; t += 256) {
                int k4 = t & 15, r = t >> 4;
                int kg = c0 + 4 * k4;
                int row = rowbase + r; if (row >= N) row = N - 1;
                float4 v;
                if (kg < 64) v = ((const float4*)(agg + (size_t)row * 64))[kg >> 2];
                else         v = ((const float4*)(h1 + (size_t)row * 64))[(kg - 64) >> 2];
                *(float4*)(Abuf + r * 68 + 4 * k4) = v;
            }
            for (int t = tid; t < 1024; t += 256) {
                int k = t >> 4, jj = t & 15;
                int kg = c0 + k;
                const float* Wsrc = (kg < 64) ? (Wrel + (size_t)kg * 64)
                                              : (Wroot + (size_t)(kg - 64) * 64);
                Wbuf[t] = ((const float4*)Wsrc)[jj];
            }
            __syncthreads();
            GEMM_INNER(16, Abuf, Wbuf)
        }
#pragma unroll
        for (int r = 0; r < 4; r++) {
            float4 o = make_float4(fmaxf(acc[r][0], 0.f), fmaxf(acc[r][1], 0.f),
                                   fmaxf(acc[r][2], 0.f), fmaxf(acc[r][3], 0.f));
            *(float4*)(h2buf + (i + 16 * r) * 68 + 4 * j) = o;
        }
    }

    // ---------- phase B: emb = normalize([x | h1 | h2] @ We + be) ----------
    float4 bv = ((const float4*)be)[j];
    float acc[4][4];
#pragma unroll
    for (int r = 0; r < 4; r++) { acc[r][0] = bv.x; acc[r][1] = bv.y; acc[r][2] = bv.z; acc[r][3] = bv.w; }

    // chunk 0: k in [0,64) from x|h1  (barrier also covers h2buf writes)
    __syncthreads();
    for (int t = tid; t < 1024; t += 256) {
        int k4 = t & 15, r = t >> 4;
        int kg = 4 * k4;
        int row = rowbase + r; if (row >= N) row = N - 1;
        float4 v;
        if (kg < 32) {
            const float* x = (row < split) ? xA + (size_t)row * 32
                                           : xB + (size_t)(row - split) * 32;
            v = ((const float4*)x)[kg >> 2];
        } else {
            v = ((const float4*)(h1 + (size_t)row * 64))[(kg - 32) >> 2];
        }
        *(float4*)(Abuf + r * 68 + 4 * k4) = v;
    }
    for (int t = tid; t < 1024; t += 256) {
        int k = t >> 4, jj = t & 15;
        Wbuf[t] = ((const float4*)(We + (size_t)k * 64))[jj];
    }
    __syncthreads();
    GEMM_INNER(16, Abuf, Wbuf)

    // chunk 1: k in [64,96) -> h1 cols 32..63 (kw = 32)
    __syncthreads();
    for (int t = tid; t < 512; t += 256) {
        int k4 = t & 7, r = t >> 3;
        int row = rowbase + r; if (row >= N) row = N - 1;
        float4 v = ((const float4*)(h1 + (size_t)row * 64))[8 + k4];
        *(float4*)(Abuf + r * 68 + 4 * k4) = v;
    }
    for (int t = tid; t < 512; t += 256) {
        int k = t >> 4, jj = t & 15;
        Wbuf[t] = ((const float4*)(We + (size_t)(64 + k) * 64))[jj];
    }
    __syncthreads();
    GEMM_INNER(8, Abuf, Wbuf)

    // chunk 2: k in [96,160) directly from h2buf (same conflict-free read pattern)
    __syncthreads();
    for (int t = tid; t < 1024; t += 256) {
        int k = t >> 4, jj = t & 15;
        Wbuf[t] = ((const float4*)(We + (size_t)(96 + k) * 64))[jj];
    }
    __syncthreads();
    GEMM_INNER(16, h2buf, Wbuf)

    // normalize epilogue
    __syncthreads();
#pragma unroll
    for (int r = 0; r < 4; r++)
#pragma unroll
        for (int c = 0; c < 4; c++)
            Abuf[(i + 16 * r) * 68 + 4 * j + c] = acc[r][c];
    __syncthreads();
    int lane = tid & 63, wv = tid >> 6;   // 4 waves, 16 rows each
    for (int rr = 0; rr < 16; rr++) {
        int r = wv * 16 + rr;
        float val = Abuf[r * 68 + lane];
        float ss = val * val;
#pragma unroll
        for (int d = 32; d > 0; d >>= 1) ss += __shfl_xor(ss, d, 64);
        int row = rowbase + r;
        if (row < N) emb[(size_t)row * 64 + lane] = val / fmaxf(sqrtf(ss), 1e-12f);
    }
}

// ================= FUSED cost + Sinkhorn: one block per pair, K in registers =================
__device__ __forceinline__ void dot_half(float kh[3][12], const float* sS, const float* sT,
                                         int ti, int tj) {
#pragma unroll
    for (int s = 0; s < 3; s++)
#pragma unroll
        for (int b = 0; b < 12; b++) kh[s][b] = 0.f;
    for (int k4 = 0; k4 < 16; k4++) {
        float4 a0 = *(const float4*)(sS + (3 * ti + 0) * 68 + 4 * k4);
        float4 a1 = *(const float4*)(sS + (3 * ti + 1) * 68 + 4 * k4);
        float4 a2 = *(const float4*)(sS + (3 * ti + 2) * 68 + 4 * k4);
#pragma unroll
        for (int b = 0; b < 12; b++) {
            float4 tb = *(const float4*)(sT + (12 * tj + b) * 68 + 4 * k4);
            kh[0][b] = fmaf(a0.x, tb.x, kh[0][b]);
            kh[0][b] = fmaf(a0.y, tb.y, kh[0][b]);
            kh[0][b] = fmaf(a0.z, tb.z, kh[0][b]);
            kh[0][b] = fmaf(a0.w, tb.w, kh[0][b]);
            kh[1][b] = fmaf(a1.x, tb.x, kh[1][b]);
            kh[1][b] = fmaf(a1.y, tb.y, kh[1][b]);
            kh[1][b] = fmaf(a1.z, tb.z, kh[1][b]);
            kh[1][b] = fmaf(a1.w, tb.w, kh[1][b]);
            kh[2][b] = fmaf(a2.x, tb.x, kh[2][b]);
            kh[2][b] = fmaf(a2.y, tb.y, kh[2][b]);
            kh[2][b] = fmaf(a2.z, tb.z, kh[2][b]);
            kh[2][b] = fmaf(a2.w, tb.w, kh[2][b]);
        }
    }
}

__device__ __forceinline__ void epi_half(float kh[3][12], const float* sqS, const float* sqT,
                                         int h, int ti, int tj, int n, int p,
                                         float* __restrict__ cost_out) {
#pragma unroll
    for (int s = 0; s < 3; s++) {
        int i = 96 * h + 3 * ti + s;
        bool rv = i < n;
        float sqi = sqS[3 * ti + s];
        float tmp[12];
#pragma unroll
        for (int b = 0; b < 12; b++) {
            int j = 12 * tj + b;
            float cd = sqrtf(fmaxf(sqi + sqT[j] - 2.f * kh[s][b], 1e-12f));
            float c = (rv && (j < n)) ? cd : ((!rv && (j >= n)) ? 0.f : 1000.f);
            tmp[b] = c;
            kh[s][b] = __expf(-10.f * c);
        }
        float* orow = cost_out + ((size_t)p * MAXN + i) * MAXN + 12 * tj;
#pragma unroll
        for (int q = 0; q < 3; q++)
            ((float4*)orow)[q] = make_float4(tmp[4 * q], tmp[4 * q + 1],
                                             tmp[4 * q + 2], tmp[4 * q + 3]);
    }
}

// 512 threads: ti = tid&31 owns rows {96h + 3ti + s}, tj = tid>>5 owns cols {12tj + b}
// LDS: sT[192][68] + sS[96][68] + sq + virt ~ 79.7 KB -> 2 blocks/CU.
// All barriers after the first global store are LDS-only (stores stream in background).
// Sinkhorn: v-update reduced fully in-wave (ti = contiguous lanes -> width-32 shfl
// butterfly); u-update pair-combined across tj-partners (lane l <-> l+32) then 8-way
// LDS reduce -> 2 barriers/iter instead of 4, vbuf eliminated.
__global__ __launch_bounds__(512, 4) void fused_cost_sinkhorn_kernel(
    const float* __restrict__ embS, const float* __restrict__ embT,
    const float* __restrict__ vraw,
    const int* __restrict__ lenS, const int* __restrict__ lenT,
    const int* __restrict__ off,
    float* __restrict__ cost_out, float* __restrict__ gamma_out,
    float* __restrict__ geds2, int Ns) {
    __shared__ __align__(16) float sT[192 * 68];
    __shared__ __align__(16) float sS[96 * 68];
    __shared__ __align__(16) float sqT[192];
    __shared__ __align__(16) float sqS[96];
    __shared__ __align__(16) float virtv[64];

    int p = blockIdx.x;
    int tid = threadIdx.x;           // 512
    int ti = tid & 31;
    int tj = tid >> 5;               // 0..15
    int n = lenS[p], m = lenT[p];
    int offs = off[p], offt = off[PAIRS + p];

    if (tid < 64) {
        float v = vraw[tid];
        float ss = v * v;
#pragma unroll
        for (int d = 32; d > 0; d >>= 1) ss += __shfl_xor(ss, d, 64);
        virtv[tid] = v / fmaxf(sqrtf(ss), 1e-12f);
    }
    __syncthreads();

    // stage T-augmented rows + S half 0
    for (int t = tid; t < 192 * 16; t += 512) {
        int j = t >> 4, q = t & 15;
        float4 vv = (j < m) ? ((const float4*)embT)[(size_t)(offt + j) * 16 + q]
                            : ((const float4*)virtv)[q];
        *(float4*)(sT + j * 68 + 4 * q) = vv;
    }
    for (int t = tid; t < 96 * 16; t += 512) {
        int r = t >> 4, q = t & 15;
        int gi = offs + r; if (gi > Ns - 1) gi = Ns - 1;
        float4 vv = ((const float4*)embS)[(size_t)gi * 16 + q];
        *(float4*)(sS + r * 68 + 4 * q) = vv;
    }
    __syncthreads();
    if (tid < 192) {
        float s = 0.f;
#pragma unroll
        for (int k = 0; k < 64; k++) { float a = sT[tid * 68 + k]; s = fmaf(a, a, s); }
        sqT[tid] = s;
    } else if (tid < 288) {
        int r = tid - 192;
        float s = 0.f;
#pragma unroll
        for (int k = 0; k < 64; k++) { float a = sS[r * 68 + k]; s = fmaf(a, a, s); }
        sqS[r] = s;
    }
    __syncthreads();

    float kf[2][3][12];

    // ---- half 0: dot, then prefetch S-half1 to regs BEFORE issuing cost stores ----
    dot_half(kf[0], sS, sT, ti, tj);
    float4 pf0, pf1, pf2;
    {
        int t0 = tid, t1 = tid + 512, t2 = tid + 1024;
        int gi0 = offs + 96 + (t0 >> 4); if (gi0 > Ns - 1) gi0 = Ns - 1;
        int gi1 = offs + 96 + (t1 >> 4); if (gi1 > Ns - 1) gi1 = Ns - 1;
        int gi2 = offs + 96 + (t2 >> 4); if (gi2 > Ns - 1) gi2 = Ns - 1;
        pf0 = ((const float4*)embS)[(size_t)gi0 * 16 + (t0 & 15)];
        pf1 = ((const float4*)embS)[(size_t)gi1 * 16 + (t1 & 15)];
        pf2 = ((const float4*)embS)[(size_t)gi2 * 16 + (t2 & 15)];
    }
    epi_half(kf[0], sqS, sqT, 0, ti, tj, n, p, cost_out);   // issues cost stores

    LDS_BAR();   // dot/epilogue LDS reads done; stores NOT drained
    {
        int t0 = tid, t1 = tid + 512, t2 = tid + 1024;
        *(float4*)(sS + (t0 >> 4) * 68 + 4 * (t0 & 15)) = pf0;
        *(float4*)(sS + (t1 >> 4) * 68 + 4 * (t1 & 15)) = pf1;
        *(float4*)(sS + (t2 >> 4) * 68 + 4 * (t2 & 15)) = pf2;
    }
    LDS_BAR();
    if (tid < 96) {
        float s = 0.f;
#pragma unroll
        for (int k = 0; k < 64; k++) { float a = sS[tid * 68 + k]; s = fmaf(a, a, s); }
        sqS[tid] = s;
    }
    LDS_BAR();

    // ---- half 1 ----
    dot_half(kf[1], sS, sT, ti, tj);
    epi_half(kf[1], sqS, sqT, 1, ti, tj, n, p, cost_out);
    LDS_BAR();   // emb tiles dead; alias scratch over sS

    float* part = sS;          // partU: [8][192] = 1536 floats
    float* ubuf = sS + 6336;   // 192 floats
    int wv = tid >> 6;         // wave id 0..7
    bool lowhalf = (tid & 63) < 32;

    if (tid < 192) ubuf[tid] = 1.f / 192.f;
    LDS_BAR();

    float vloc[12];
    for (int it = 0; it < 8; it++) {
        // ---- v = 1 / (K^T u): column sums via width-32 butterfly over ti-lanes ----
        float uloc[6];
#pragma unroll
        for (int h = 0; h < 2; h++)
#pragma unroll
            for (int s = 0; s < 3; s++) uloc[3 * h + s] = ubuf[96 * h + 3 * ti + s];
        float a[12];
#pragma unroll
        for (int b = 0; b < 12; b++) {
            float x = 0.f;
#pragma unroll
            for (int h = 0; h < 2; h++)
#pragma unroll
                for (int s = 0; s < 3; s++) x = fmaf(kf[h][s][b], uloc[3 * h + s], x);
            a[b] = x;
        }
#pragma unroll
        for (int d = 1; d < 32; d <<= 1)
#pragma unroll
            for (int b = 0; b < 12; b++) a[b] += __shfl_xor(a[b], d, 32);
#pragma unroll
        for (int b = 0; b < 12; b++) vloc[b] = 1.f / a[b];
        // ---- u = 1 / (K v): row sums; pair-combine tj-partner (l <-> l+32), 8-way LDS ----
        float r[6];
#pragma unroll
        for (int h = 0; h < 2; h++)
#pragma unroll
            for (int s = 0; s < 3; s++) {
                float x = 0.f;
#pragma unroll
                for (int b = 0; b < 12; b++) x = fmaf(kf[h][s][b], vloc[b], x);
                r[3 * h + s] = x;
            }
#pragma unroll
        for (int q = 0; q < 6; q++) r[q] += __shfl_xor(r[q], 32, 64);
        if (lowhalf) {
#pragma unroll
            for (int h = 0; h < 2; h++)
#pragma unroll
                for (int s = 0; s < 3; s++)
                    part[wv * 192 + 96 * h + 3 * ti + s] = r[3 * h + s];
        }
        LDS_BAR();
        if (tid < 192) {
            float s = part[tid] + part[192 + tid] + part[384 + tid] + part[576 + tid]
                    + part[768 + tid] + part[960 + tid] + part[1152 + tid] + part[1344 + tid];
            ubuf[tid] = 1.f / s;
        }
        LDS_BAR();
    }

    // ---- gamma = u .* K .* v, geds2 = sum(gamma * cost) / (n + m) ----
    // vloc (final v for this thread's columns) already in registers.
    float accg = 0.f;
#pragma unroll
    for (int h = 0; h < 2; h++)
#pragma unroll
        for (int s = 0; s < 3; s++) {
            int i = 96 * h + 3 * ti + s;
            float ui = ubuf[i];
            float tmp[12];
#pragma unroll
            for (int b = 0; b < 12; b++) {
                float Kij = kf[h][s][b];
                float gg = ui * Kij * vloc[b];
                tmp[b] = gg;
                if (Kij > 0.f) accg = fmaf(gg, -0.1f * __logf(Kij), accg);
            }
            float* grow = gamma_out + ((size_t)p * MAXN + i) * MAXN + 12 * tj;
#pragma unroll
            for (int q = 0; q < 3; q++)
                ((float4*)grow)[q] = make_float4(tmp[4 * q], tmp[4 * q + 1],
                                                 tmp[4 * q + 2], tmp[4 * q + 3]);
        }
#pragma unroll
    for (int d = 32; d > 0; d >>= 1) accg += __shfl_xor(accg, d, 64);
    if ((tid & 63) == 0) sqS[tid >> 6] = accg;
    LDS_BAR();
    if (tid == 0) {
        float s = 0.f;
        for (int w = 0; w < 8; w++) s += sqS[w];
        geds2[p] = s / (float)(n + m);
    }
}

extern "C" void kernel_launch(void* const* d_in, const int* in_sizes, int n_in,
                              void* d_out, int out_size, void* d_ws, size_t ws_size,
                              hipStream_t stream) {
    const float* x_s     = (const float*)d_in[0];
    const float* x_t     = (const float*)d_in[1];
    const float* W_rel0  = (const float*)d_in[2];
    const float* b_rel0  = (const float*)d_in[3];
    const float* W_root0 = (const float*)d_in[4];
    const float* W_rel1  = (const float*)d_in[5];
    const float* b_rel1  = (const float*)d_in[6];
    const float* W_root1 = (const float*)d_in[7];
    const float* W_e     = (const float*)d_in[8];
    const float* b_e     = (const float*)d_in[9];
    const float* virt    = (const float*)d_in[10];
    const int*   ei_s    = (const int*)d_in[11];
    const int*   ei_t    = (const int*)d_in[12];
    const int*   len_s   = (const int*)d_in[13];
    const int*   len_t   = (const int*)d_in[14];

    int Ns = in_sizes[0] / 32;
    int Nt = in_sizes[1] / 32;
    int Es = in_sizes[11] / 2;
    int Et = in_sizes[12] / 2;
    int Ntot = Ns + Nt;
    int Etot = Es + Et;

    // ---- workspace layout ----
    char* w = (char*)d_ws;
    int* off  = (int*)w;              w += 1024 * 4;
    int* bsum = (int*)w;              w += 256 * 4;
    int* rs   = (int*)w;              w += (size_t)Ntot * 4;
    int* cur  = (int*)w;              w += (size_t)Ntot * 4;
    int* src  = (int*)w;              w += (size_t)Etot * 4;
    w = (char*)(((size_t)w + 255) & ~(size_t)255);
    float* agg = (float*)w;           w += (size_t)Ntot * 64 * 4;  // gather out; later emb (in-place)
    float* h1  = (float*)w;           w += (size_t)Ntot * 64 * 4;

    float* out_gamma = (float*)d_out;
    float* out_cost  = out_gamma + (size_t)PAIRS * MAXN * MAXN;
    float* out_geds  = out_cost + (size_t)PAIRS * MAXN * MAXN;

    offsets_kernel<<<1, PAIRS, 0, stream>>>(len_s, len_t, off);

    // ---- combined CSR build ----
    hipMemsetAsync(rs, 0, (size_t)Ntot * 4, stream);
    count2_kernel<<<(Etot + 255) / 256, 256, 0, stream>>>(ei_s, ei_t, rs, Es, Et, Ns);
    int nb = (Ntot + 1023) / 1024;
    scan1_kernel<<<nb, 256, 0, stream>>>(rs, bsum, Ntot);
    scan2_kernel<<<1, 256, 0, stream>>>(bsum, nb);
    scan3_kernel<<<(Ntot + 255) / 256, 256, 0, stream>>>(rs, bsum, cur, Ntot);
    fill2_kernel<<<(Etot + 255) / 256, 256, 0, stream>>>(ei_s, ei_t, cur, src, Es, Et, Ns);

    int gblk = (Ntot + 63) / 64;

    // ---- combined GNN ----
    gather_kernel<32><<<(int)(((long long)Ntot * 8 + 255) / 256), 256, 0, stream>>>(
        x_s, x_t, Ns, rs, cur, src, agg, Ntot);
    lin_gemm_kernel<32><<<gblk, 256, 0, stream>>>(
        agg, x_s, x_t, Ns, W_rel0, b_rel0, W_root0, h1, Ntot);
    gather_kernel<64><<<(int)(((long long)Ntot * 16 + 255) / 256), 256, 0, stream>>>(
        h1, h1, Ns, rs, cur, src, agg, Ntot);
    // fused layer2 + emb: reads agg (own rows) + h1 + x, writes emb in-place into agg
    lin64_emb_kernel<<<gblk, 256, 0, stream>>>(
        agg, h1, x_s, x_t, Ns, W_rel1, b_rel1, W_root1, W_e, b_e, agg, Ntot);

    // ---- fused cost + sinkhorn ----
    fused_cost_sinkhorn_kernel<<<PAIRS, 512, 0, stream>>>(
        agg, agg + (size_t)Ns * 64, virt, len_s, len_t, off,
        out_cost, out_gamma, out_geds, Ns);
}

// Round 10
// 530.583 us; speedup vs baseline: 1.1574x; 1.1176x over previous
//
#include <hip/hip_runtime.h>
#include <math.h>

#define PAIRS 512
#define MAXN 192

// barrier with LDS ordering only — does NOT drain vmcnt, so global stores keep streaming
#define LDS_BAR() asm volatile("s_waitcnt lgkmcnt(0)\n\ts_barrier" ::: "memory")

// ---------------- offsets: exclusive prefix sums of len_s / len_t (shfl scan) ----------------
__global__ void offsets_kernel(const int* __restrict__ ls, const int* __restrict__ lt,
                               int* __restrict__ off) {
    __shared__ int wa[8], wb[8];
    int t = threadIdx.x;  // 512
    int a = ls[t], b = lt[t];
    int ia = a, ib = b;
#pragma unroll
    for (int d = 1; d < 64; d <<= 1) {
        int xa = __shfl_up(ia, d, 64);
        int xb = __shfl_up(ib, d, 64);
        if ((t & 63) >= d) { ia += xa; ib += xb; }
    }
    if ((t & 63) == 63) { wa[t >> 6] = ia; wb[t >> 6] = ib; }
    __syncthreads();
    int pa = 0, pb = 0;
    for (int w = 0; w < (t >> 6); w++) { pa += wa[w]; pb += wb[w]; }
    off[t] = pa + ia - a;          // exclusive
    off[PAIRS + t] = pb + ib - b;
}

// ================= CSR build over combined row space [0,Ns) ∪ [Ns,Ns+Nt) =================
__global__ __launch_bounds__(256) void count2_kernel(const int* __restrict__ eiS,
                                                     const int* __restrict__ eiT,
                                                     int* __restrict__ cnt,
                                                     int Es, int Et, int split) {
    int e = blockIdx.x * 256 + threadIdx.x;
    if (e < Es) atomicAdd(&cnt[eiS[Es + e]], 1);
    else if (e < Es + Et) atomicAdd(&cnt[split + eiT[Et + (e - Es)]], 1);
}

__global__ __launch_bounds__(256) void scan1_kernel(int* __restrict__ data,
                                                    int* __restrict__ blockSums, int N) {
    __shared__ int sc[256];
    int t = threadIdx.x;
    int base = blockIdx.x * 1024;
    int v[4];
    int s = 0;
#pragma unroll
    for (int q = 0; q < 4; q++) {
        int i = base + t * 4 + q;
        v[q] = (i < N) ? data[i] : 0;
        s += v[q];
    }
    sc[t] = s;
    __syncthreads();
    for (int d = 1; d < 256; d <<= 1) {
        int x = (t >= d) ? sc[t - d] : 0;
        __syncthreads();
        sc[t] += x;
        __syncthreads();
    }
    int excl = sc[t] - s;
#pragma unroll
    for (int q = 0; q < 4; q++) {
        int i = base + t * 4 + q;
        if (i < N) { data[i] = excl; excl += v[q]; }
    }
    if (t == 255) blockSums[blockIdx.x] = sc[255];
}

__global__ void scan2_kernel(int* __restrict__ blockSums, int B) {
    __shared__ int sh[256];
    int t = threadIdx.x;  // 256
    int v = (t < B) ? blockSums[t] : 0;
    sh[t] = v;
    __syncthreads();
    for (int d = 1; d < 256; d <<= 1) {
        int x = (t >= d) ? sh[t - d] : 0;
        __syncthreads();
        sh[t] += x;
        __syncthreads();
    }
    if (t < B) blockSums[t] = sh[t] - v;
}

__global__ __launch_bounds__(256) void scan3_kernel(int* __restrict__ data,
                                                    const int* __restrict__ blockSums,
                                                    int* __restrict__ cursor, int N) {
    int i = blockIdx.x * 256 + threadIdx.x;
    if (i < N) {
        int v = data[i] + blockSums[i >> 10];
        data[i] = v;
        cursor[i] = v;
    }
}

__global__ __launch_bounds__(256) void fill2_kernel(const int* __restrict__ eiS,
                                                    const int* __restrict__ eiT,
                                                    int* __restrict__ cursor,
                                                    int* __restrict__ src,
                                                    int Es, int Et, int split) {
    int e = blockIdx.x * 256 + threadIdx.x;
    if (e < Es) {
        int p = atomicAdd(&cursor[eiS[Es + e]], 1);
        src[p] = eiS[e];
    } else if (e < Es + Et) {
        int ee = e - Es;
        int p = atomicAdd(&cursor[split + eiT[Et + ee]], 1);
        src[p] = eiT[ee];
    }
}

// ================= gather aggregation (combined rows), float4-vectorized =================
template <int F>
__global__ __launch_bounds__(256) void gather_kernel(const float* __restrict__ featA,
                                                     const float* __restrict__ featB,
                                                     int split,
                                                     const int* __restrict__ rs,
                                                     const int* __restrict__ re,
                                                     const int* __restrict__ src,
                                                     float* __restrict__ agg, int N) {
    constexpr int F4 = F / 4;
    int gid = blockIdx.x * 256 + threadIdx.x;
    int row = gid / F4;
    int lane = threadIdx.x & (F4 - 1);
    if (row >= N) return;
    int b = rs[row], e = re[row];
    int cnt = e - b;
    const float* feat = (row < split) ? featA : featB;
    int pre = cnt < F4 ? cnt : F4;
    int sidx = (lane < cnt) ? src[b + lane] : 0;
    float4 acc = make_float4(0.f, 0.f, 0.f, 0.f);
    for (int q = 0; q < pre; q++) {
        int s = __shfl(sidx, q, F4);
        float4 v = ((const float4*)(feat + (size_t)s * F))[lane];
        acc.x += v.x; acc.y += v.y; acc.z += v.z; acc.w += v.w;
    }
    for (int q = b + F4; q < e; q++) {
        int s = src[q];
        float4 v = ((const float4*)(feat + (size_t)s * F))[lane];
        acc.x += v.x; acc.y += v.y; acc.z += v.z; acc.w += v.w;
    }
    ((float4*)(agg + (size_t)row * F))[lane] = acc;
}

// ========== register-tile GEMMs: 64 rows × 64 cols / block, 256 threads ==========
// thread map: i = tid&15 -> rows {i, i+16, i+32, i+48} ; j = tid>>4 -> cols 4j..4j+3
// A (and h2) row-major in LDS, stride 68 (float4-aligned; strided row ownership ->
//   A-read bank base (4i+4k4)%32: lanes i,i+8 pair = 2-way = free)

#define FMA_ROW(r, av)                                     \
    acc[r][0] = fmaf(av.x, w0.x, acc[r][0]);               \
    acc[r][1] = fmaf(av.x, w0.y, acc[r][1]);               \
    acc[r][2] = fmaf(av.x, w0.z, acc[r][2]);               \
    acc[r][3] = fmaf(av.x, w0.w, acc[r][3]);               \
    acc[r][0] = fmaf(av.y, w1.x, acc[r][0]);               \
    acc[r][1] = fmaf(av.y, w1.y, acc[r][1]);               \
    acc[r][2] = fmaf(av.y, w1.z, acc[r][2]);               \
    acc[r][3] = fmaf(av.y, w1.w, acc[r][3]);               \
    acc[r][0] = fmaf(av.z, w2.x, acc[r][0]);               \
    acc[r][1] = fmaf(av.z, w2.y, acc[r][1]);               \
    acc[r][2] = fmaf(av.z, w2.z, acc[r][2]);               \
    acc[r][3] = fmaf(av.z, w2.w, acc[r][3]);               \
    acc[r][0] = fmaf(av.w, w3.x, acc[r][0]);               \
    acc[r][1] = fmaf(av.w, w3.y, acc[r][1]);               \
    acc[r][2] = fmaf(av.w, w3.z, acc[r][2]);               \
    acc[r][3] = fmaf(av.w, w3.w, acc[r][3]);

#define GEMM_INNER(KW4, AKP, WBP)                                          \
    _Pragma("unroll") for (int k4 = 0; k4 < (KW4); k4++) {                 \
        float4 a0 = *(const float4*)((AKP) + (i)      * 68 + 4 * k4);      \
        float4 a1 = *(const float4*)((AKP) + (i + 16) * 68 + 4 * k4);      \
        float4 a2 = *(const float4*)((AKP) + (i + 32) * 68 + 4 * k4);      \
        float4 a3 = *(const float4*)((AKP) + (i + 48) * 68 + 4 * k4);      \
        float4 w0 = (WBP)[(4 * k4 + 0) * 16 + j];                          \
        float4 w1 = (WBP)[(4 * k4 + 1) * 16 + j];                          \
        float4 w2 = (WBP)[(4 * k4 + 2) * 16 + j];                          \
        float4 w3 = (WBP)[(4 * k4 + 3) * 16 + j];                          \
        FMA_ROW(0, a0) FMA_ROW(1, a1) FMA_ROW(2, a2) FMA_ROW(3, a3)        \
    }

// h_out = relu([agg | hin] @ [Wrel ; Wroot] + b)   (K' = 2*KIN, chunks of 64)
template <int KIN>
__global__ __launch_bounds__(256) void lin_gemm_kernel(const float* __restrict__ agg,
    const float* __restrict__ hinA, const float* __restrict__ hinB, int split,
    const float* __restrict__ Wrel, const float* __restrict__ brel,
    const float* __restrict__ Wroot, float* __restrict__ hout, int N) {
    __shared__ float Abuf[64 * 68];
    __shared__ float4 Wbuf[64 * 16];
    int tid = threadIdx.x;
    int i = tid & 15, j = tid >> 4;
    int rowbase = blockIdx.x * 64;
    float4 bv = ((const float4*)brel)[j];
    float acc[4][4];
#pragma unroll
    for (int r = 0; r < 4; r++) { acc[r][0] = bv.x; acc[r][1] = bv.y; acc[r][2] = bv.z; acc[r][3] = bv.w; }

    for (int c0 = 0; c0 < 2 * KIN; c0 += 64) {
        __syncthreads();
        for (int t = tid; t < 1024; t += 256) {
            int k4 = t & 15, r = t >> 4;
            int kg = c0 + 4 * k4;
            int row = rowbase + r; if (row >= N) row = N - 1;
            float4 v;
            if (kg < KIN) {
                v = ((const float4*)(agg + (size_t)row * KIN))[kg >> 2];
            } else {
                int kk = kg - KIN;
                const float* h = (row < split) ? hinA + (size_t)row * KIN
                                               : hinB + (size_t)(row - split) * KIN;
                v = ((const float4*)h)[kk >> 2];
            }
            *(float4*)(Abuf + r * 68 + 4 * k4) = v;
        }
        for (int t = tid; t < 1024; t += 256) {
            int k = t >> 4, jj = t & 15;
            int kg = c0 + k;
            const float* Wsrc = (kg < KIN) ? (Wrel + (size_t)kg * 64)
                                           : (Wroot + (size_t)(kg - KIN) * 64);
            Wbuf[t] = ((const float4*)Wsrc)[jj];
        }
        __syncthreads();
        GEMM_INNER(16, Abuf, Wbuf)
    }
#pragma unroll
    for (int r = 0; r < 4; r++) {
        int row = rowbase + i + 16 * r;
        if (row < N) {
            float4 o = make_float4(fmaxf(acc[r][0], 0.f), fmaxf(acc[r][1], 0.f),
                                   fmaxf(acc[r][2], 0.f), fmaxf(acc[r][3], 0.f));
            ((float4*)(hout + (size_t)row * 64))[j] = o;
        }
    }
}

// ===== FUSED layer2 + emb: h2 kept row-major in LDS; emb = normalize([x|h1|h2]@We+be) in-place =====
__global__ __launch_bounds__(256) void lin64_emb_kernel(
    const float* __restrict__ agg, const float* __restrict__ h1,
    const float* __restrict__ xA, const float* __restrict__ xB, int split,
    const float* __restrict__ Wrel, const float* __restrict__ brel,
    const float* __restrict__ Wroot,
    const float* __restrict__ We, const float* __restrict__ be,
    float* __restrict__ emb, int N) {
    __shared__ float Abuf[64 * 68];
    __shared__ float4 Wbuf[64 * 16];
    __shared__ float h2buf[64 * 68];   // row-major [row][k], stride 68
    int tid = threadIdx.x;
    int i = tid & 15, j = tid >> 4;
    int rowbase = blockIdx.x * 64;

    // ---------- phase A: h2 = relu([agg | h1] @ [Wrel;Wroot] + brel) ----------
    {
        float4 bv = ((const float4*)brel)[j];
        float acc[4][4];
#pragma unroll
        for (int r = 0; r < 4; r++) { acc[r][0] = bv.x; acc[r][1] = bv.y; acc[r][2] = bv.z; acc[r][3] = bv.w; }

        for (int c0 = 0; c0 < 128; c0 += 64) {
            __syncthreads();
            for (int t = tid; t < 1024; t += 256) {
                int k4 = t & 15, r = t >> 4;
                int kg = c0 + 4 * k4;
                int row = rowbase + r; if (row >= N) row = N - 1;
                float4 v;
                if (kg < 64) v = ((const float4*)(agg + (size_t)row * 64))[kg >> 2];
                else         v = ((const float4*)(h1 + (size_t)row * 64))[(kg - 64) >> 2];
                *(float4*)(Abuf + r * 68 + 4 * k4) = v;
            }
            for (int t = tid; t < 1024; t += 256) {
                int k = t >> 4, jj = t & 15;
                int kg = c0 + k;
                const float* Wsrc = (kg < 64) ? (Wrel + (size_t)kg * 64)
                                              : (Wroot + (size_t)(kg - 64) * 64);
                Wbuf[t] = ((const float4*)Wsrc)[jj];
            }
            __syncthreads();
            GEMM_INNER(16, Abuf, Wbuf)
        }
#pragma unroll
        for (int r = 0; r < 4; r++) {
            float4 o = make_float4(fmaxf(acc[r][0], 0.f), fmaxf(acc[r][1], 0.f),
                                   fmaxf(acc[r][2], 0.f), fmaxf(acc[r][3], 0.f));
            *(float4*)(h2buf + (i + 16 * r) * 68 + 4 * j) = o;
        }
    }

    // ---------- phase B: emb = normalize([x | h1 | h2] @ We + be) ----------
    float4 bv = ((const float4*)be)[j];
    float acc[4][4];
#pragma unroll
    for (int r = 0; r < 4; r++) { acc[r][0] = bv.x; acc[r][1] = bv.y; acc[r][2] = bv.z; acc[r][3] = bv.w; }

    // chunk 0: k in [0,64) from x|h1  (barrier also covers h2buf writes)
    __syncthreads();
    for (int t = tid; t < 1024; t += 256) {
        int k4 = t & 15, r = t >> 4;
        int kg = 4 * k4;
        int row = rowbase + r; if (row >= N) row = N - 1;
        float4 v;
        if (kg < 32) {
            const float* x = (row < split) ? xA + (size_t)row * 32
                                           : xB + (size_t)(row - split) * 32;
            v = ((const float4*)x)[kg >> 2];
        } else {
            v = ((const float4*)(h1 + (size_t)row * 64))[(kg - 32) >> 2];
        }
        *(float4*)(Abuf + r * 68 + 4 * k4) = v;
    }
    for (int t = tid; t < 1024; t += 256) {
        int k = t >> 4, jj = t & 15;
        Wbuf[t] = ((const float4*)(We + (size_t)k * 64))[jj];
    }
    __syncthreads();
    GEMM_INNER(16, Abuf, Wbuf)

    // chunk 1: k in [64,96) -> h1 cols 32..63 (kw = 32)
    __syncthreads();
    for (int t = tid; t < 512; t += 256) {
        int k4 = t & 7, r = t >> 3;
        int row = rowbase + r; if (row >= N) row = N - 1;
        float4 v = ((const float4*)(h1 + (size_t)row * 64))[8 + k4];
        *(float4*)(Abuf + r * 68 + 4 * k4) = v;
    }
    for (int t = tid; t < 512; t += 256) {
        int k = t >> 4, jj = t & 15;
        Wbuf[t] = ((const float4*)(We + (size_t)(64 + k) * 64))[jj];
    }
    __syncthreads();
    GEMM_INNER(8, Abuf, Wbuf)

    // chunk 2: k in [96,160) directly from h2buf (same conflict-free read pattern)
    __syncthreads();
    for (int t = tid; t < 1024; t += 256) {
        int k = t >> 4, jj = t & 15;
        Wbuf[t] = ((const float4*)(We + (size_t)(96 + k) * 64))[jj];
    }
    __syncthreads();
    GEMM_INNER(16, h2buf, Wbuf)

    // normalize epilogue
    __syncthreads();
#pragma unroll
    for (int r = 0; r < 4; r++)
#pragma unroll
        for (int c = 0; c < 4; c++)
            Abuf[(i + 16 * r) * 68 + 4 * j + c] = acc[r][c];
    __syncthreads();
    int lane = tid & 63, wv = tid >> 6;   // 4 waves, 16 rows each
    for (int rr = 0; rr < 16; rr++) {
        int r = wv * 16 + rr;
        float val = Abuf[r * 68 + lane];
        float ss = val * val;
#pragma unroll
        for (int d = 32; d > 0; d >>= 1) ss += __shfl_xor(ss, d, 64);
        int row = rowbase + r;
        if (row < N) emb[(size_t)row * 64 + lane] = val / fmaxf(sqrtf(ss), 1e-12f);
    }
}

// ================= FUSED cost + Sinkhorn: one block per pair, K in registers =================
__device__ __forceinline__ void dot_half(float kh[3][12], const float* sS, const float* sT,
                                         int ti, int tj) {
#pragma unroll
    for (int s = 0; s < 3; s++)
#pragma unroll
        for (int b = 0; b < 12; b++) kh[s][b] = 0.f;
    for (int k4 = 0; k4 < 16; k4++) {
        float4 a0 = *(const float4*)(sS + (3 * ti + 0) * 68 + 4 * k4);
        float4 a1 = *(const float4*)(sS + (3 * ti + 1) * 68 + 4 * k4);
        float4 a2 = *(const float4*)(sS + (3 * ti + 2) * 68 + 4 * k4);
#pragma unroll
        for (int b = 0; b < 12; b++) {
            float4 tb = *(const float4*)(sT + (12 * tj + b) * 68 + 4 * k4);
            kh[0][b] = fmaf(a0.x, tb.x, kh[0][b]);
            kh[0][b] = fmaf(a0.y, tb.y, kh[0][b]);
            kh[0][b] = fmaf(a0.z, tb.z, kh[0][b]);
            kh[0][b] = fmaf(a0.w, tb.w, kh[0][b]);
            kh[1][b] = fmaf(a1.x, tb.x, kh[1][b]);
            kh[1][b] = fmaf(a1.y, tb.y, kh[1][b]);
            kh[1][b] = fmaf(a1.z, tb.z, kh[1][b]);
            kh[1][b] = fmaf(a1.w, tb.w, kh[1][b]);
            kh[2][b] = fmaf(a2.x, tb.x, kh[2][b]);
            kh[2][b] = fmaf(a2.y, tb.y, kh[2][b]);
            kh[2][b] = fmaf(a2.z, tb.z, kh[2][b]);
            kh[2][b] = fmaf(a2.w, tb.w, kh[2][b]);
        }
    }
}

__device__ __forceinline__ void epi_half(float kh[3][12], const float* sqS, const float* sqT,
                                         int h, int ti, int tj, int n, int p,
                                         float* __restrict__ cost_out) {
#pragma unroll
    for (int s = 0; s < 3; s++) {
        int i = 96 * h + 3 * ti + s;
        bool rv = i < n;
        float sqi = sqS[3 * ti + s];
        float tmp[12];
#pragma unroll
        for (int b = 0; b < 12; b++) {
            int j = 12 * tj + b;
            float cd = sqrtf(fmaxf(sqi + sqT[j] - 2.f * kh[s][b], 1e-12f));
            float c = (rv && (j < n)) ? cd : ((!rv && (j >= n)) ? 0.f : 1000.f);
            tmp[b] = c;
            kh[s][b] = __expf(-10.f * c);
        }
        float* orow = cost_out + ((size_t)p * MAXN + i) * MAXN + 12 * tj;
#pragma unroll
        for (int q = 0; q < 3; q++)
            ((float4*)orow)[q] = make_float4(tmp[4 * q], tmp[4 * q + 1],
                                             tmp[4 * q + 2], tmp[4 * q + 3]);
    }
}

// 512 threads: ti = tid&31 owns rows {96h + 3ti + s}, tj = tid>>5 owns cols {12tj + b}
// LDS: sT[192][68] + sS[96][68] + sq + virt ~ 79.7 KB -> 2 blocks/CU.
// All barriers after the first global store are LDS-only (stores stream in background).
__global__ __launch_bounds__(512, 4) void fused_cost_sinkhorn_kernel(
    const float* __restrict__ embS, const float* __restrict__ embT,
    const float* __restrict__ vraw,
    const int* __restrict__ lenS, const int* __restrict__ lenT,
    const int* __restrict__ off,
    float* __restrict__ cost_out, float* __restrict__ gamma_out,
    float* __restrict__ geds2, int Ns) {
    __shared__ __align__(16) float sT[192 * 68];
    __shared__ __align__(16) float sS[96 * 68];
    __shared__ __align__(16) float sqT[192];
    __shared__ __align__(16) float sqS[96];
    __shared__ __align__(16) float virtv[64];

    int p = blockIdx.x;
    int tid = threadIdx.x;           // 512
    int ti = tid & 31;
    int tj = tid >> 5;               // 0..15
    int n = lenS[p], m = lenT[p];
    int offs = off[p], offt = off[PAIRS + p];

    if (tid < 64) {
        float v = vraw[tid];
        float ss = v * v;
#pragma unroll
        for (int d = 32; d > 0; d >>= 1) ss += __shfl_xor(ss, d, 64);
        virtv[tid] = v / fmaxf(sqrtf(ss), 1e-12f);
    }
    __syncthreads();

    // stage T-augmented rows + S half 0
    for (int t = tid; t < 192 * 16; t += 512) {
        int j = t >> 4, q = t & 15;
        float4 vv = (j < m) ? ((const float4*)embT)[(size_t)(offt + j) * 16 + q]
                            : ((const float4*)virtv)[q];
        *(float4*)(sT + j * 68 + 4 * q) = vv;
    }
    for (int t = tid; t < 96 * 16; t += 512) {
        int r = t >> 4, q = t & 15;
        int gi = offs + r; if (gi > Ns - 1) gi = Ns - 1;
        float4 vv = ((const float4*)embS)[(size_t)gi * 16 + q];
        *(float4*)(sS + r * 68 + 4 * q) = vv;
    }
    __syncthreads();
    if (tid < 192) {
        float s = 0.f;
#pragma unroll
        for (int k = 0; k < 64; k++) { float a = sT[tid * 68 + k]; s = fmaf(a, a, s); }
        sqT[tid] = s;
    } else if (tid < 288) {
        int r = tid - 192;
        float s = 0.f;
#pragma unroll
        for (int k = 0; k < 64; k++) { float a = sS[r * 68 + k]; s = fmaf(a, a, s); }
        sqS[r] = s;
    }
    __syncthreads();

    float kf[2][3][12];

    // ---- half 0: dot, then prefetch S-half1 to regs BEFORE issuing cost stores ----
    dot_half(kf[0], sS, sT, ti, tj);
    float4 pf0, pf1, pf2;
    {
        int t0 = tid, t1 = tid + 512, t2 = tid + 1024;
        int gi0 = offs + 96 + (t0 >> 4); if (gi0 > Ns - 1) gi0 = Ns - 1;
        int gi1 = offs + 96 + (t1 >> 4); if (gi1 > Ns - 1) gi1 = Ns - 1;
        int gi2 = offs + 96 + (t2 >> 4); if (gi2 > Ns - 1) gi2 = Ns - 1;
        pf0 = ((const float4*)embS)[(size_t)gi0 * 16 + (t0 & 15)];
        pf1 = ((const float4*)embS)[(size_t)gi1 * 16 + (t1 & 15)];
        pf2 = ((const float4*)embS)[(size_t)gi2 * 16 + (t2 & 15)];
    }
    epi_half(kf[0], sqS, sqT, 0, ti, tj, n, p, cost_out);   // issues cost stores

    LDS_BAR();   // dot/epilogue LDS reads done; stores NOT drained
    {
        int t0 = tid, t1 = tid + 512, t2 = tid + 1024;
        *(float4*)(sS + (t0 >> 4) * 68 + 4 * (t0 & 15)) = pf0;
        *(float4*)(sS + (t1 >> 4) * 68 + 4 * (t1 & 15)) = pf1;
        *(float4*)(sS + (t2 >> 4) * 68 + 4 * (t2 & 15)) = pf2;
    }
    LDS_BAR();
    if (tid < 96) {
        float s = 0.f;
#pragma unroll
        for (int k = 0; k < 64; k++) { float a = sS[tid * 68 + k]; s = fmaf(a, a, s); }
        sqS[tid] = s;
    }
    LDS_BAR();

    // ---- half 1 ----
    dot_half(kf[1], sS, sT, ti, tj);
    epi_half(kf[1], sqS, sqT, 1, ti, tj, n, p, cost_out);
    LDS_BAR();   // emb tiles dead; alias scratch over sS / sqT

    float* part = sS;          // partV: [192][33] (6336 f) / partU: [16][192] (3072 f)
    float* ubuf = sS + 6336;   // 192 floats
    float* vbuf = sqT;         // 192 floats

    if (tid < 192) ubuf[tid] = 1.f / 192.f;
    LDS_BAR();

    for (int it = 0; it < 8; it++) {
        // ---- v = 1 / (K^T u) ----
        float uloc[6];
#pragma unroll
        for (int h = 0; h < 2; h++)
#pragma unroll
            for (int s = 0; s < 3; s++) uloc[3 * h + s] = ubuf[96 * h + 3 * ti + s];
#pragma unroll
        for (int b = 0; b < 12; b++) {
            float a = 0.f;
#pragma unroll
            for (int h = 0; h < 2; h++)
#pragma unroll
                for (int s = 0; s < 3; s++) a = fmaf(kf[h][s][b], uloc[3 * h + s], a);
            part[(12 * tj + b) * 33 + ti] = a;
        }
        LDS_BAR();
        if (tid < 192) {
            float s = 0.f;
#pragma unroll
            for (int g = 0; g < 32; g++) s += part[tid * 33 + g];
            vbuf[tid] = 1.f / s;
        }
        LDS_BAR();
        // ---- u = 1 / (K v) ----
        float vloc[12];
        {
            float4 va = *(const float4*)(vbuf + 12 * tj);
            float4 vb = *(const float4*)(vbuf + 12 * tj + 4);
            float4 vc = *(const float4*)(vbuf + 12 * tj + 8);
            vloc[0] = va.x; vloc[1] = va.y; vloc[2] = va.z; vloc[3] = va.w;
            vloc[4] = vb.x; vloc[5] = vb.y; vloc[6] = vb.z; vloc[7] = vb.w;
            vloc[8] = vc.x; vloc[9] = vc.y; vloc[10] = vc.z; vloc[11] = vc.w;
        }
#pragma unroll
        for (int h = 0; h < 2; h++)
#pragma unroll
            for (int s = 0; s < 3; s++) {
                float a = 0.f;
#pragma unroll
                for (int b = 0; b < 12; b++) a = fmaf(kf[h][s][b], vloc[b], a);
                part[tj * 192 + 96 * h + 3 * ti + s] = a;
            }
        LDS_BAR();
        if (tid < 192) {
            float s = 0.f;
#pragma unroll
            for (int g = 0; g < 16; g++) s += part[g * 192 + tid];
            ubuf[tid] = 1.f / s;
        }
        LDS_BAR();
    }

    // ---- gamma = u .* K .* v, geds2 = sum(gamma * cost) / (n + m) ----
    float vloc[12];
    {
        float4 va = *(const float4*)(vbuf + 12 * tj);
        float4 vb = *(const float4*)(vbuf + 12 * tj + 4);
        float4 vc = *(const float4*)(vbuf + 12 * tj + 8);
        vloc[0] = va.x; vloc[1] = va.y; vloc[2] = va.z; vloc[3] = va.w;
        vloc[4] = vb.x; vloc[5] = vb.y; vloc[6] = vb.z; vloc[7] = vb.w;
        vloc[8] = vc.x; vloc[9] = vc.y; vloc[10] = vc.z; vloc[11] = vc.w;
    }
    float accg = 0.f;
#pragma unroll
    for (int h = 0; h < 2; h++)
#pragma unroll
        for (int s = 0; s < 3; s++) {
            int i = 96 * h + 3 * ti + s;
            float ui = ubuf[i];
            float tmp[12];
#pragma unroll
            for (int b = 0; b < 12; b++) {
                float Kij = kf[h][s][b];
                float gg = ui * Kij * vloc[b];
                tmp[b] = gg;
                if (Kij > 0.f) accg = fmaf(gg, -0.1f * __logf(Kij), accg);
            }
            float* grow = gamma_out + ((size_t)p * MAXN + i) * MAXN + 12 * tj;
#pragma unroll
            for (int q = 0; q < 3; q++)
                ((float4*)grow)[q] = make_float4(tmp[4 * q], tmp[4 * q + 1],
                                                 tmp[4 * q + 2], tmp[4 * q + 3]);
        }
#pragma unroll
    for (int d = 32; d > 0; d >>= 1) accg += __shfl_xor(accg, d, 64);
    if ((tid & 63) == 0) sqS[tid >> 6] = accg;
    LDS_BAR();
    if (tid == 0) {
        float s = 0.f;
        for (int w = 0; w < 8; w++) s += sqS[w];
        geds2[p] = s / (float)(n + m);
    }
}

extern "C" void kernel_launch(void* const* d_in, const int* in_sizes, int n_in,
                              void* d_out, int out_size, void* d_ws, size_t ws_size,
                              hipStream_t stream) {
    const float* x_s     = (const float*)d_in[0];
    const float* x_t     = (const float*)d_in[1];
    const float* W_rel0  = (const float*)d_in[2];
    const float* b_rel0  = (const float*)d_in[3];
    const float* W_root0 = (const float*)d_in[4];
    const float* W_rel1  = (const float*)d_in[5];
    const float* b_rel1  = (const float*)d_in[6];
    const float* W_root1 = (const float*)d_in[7];
    const float* W_e     = (const float*)d_in[8];
    const float* b_e     = (const float*)d_in[9];
    const float* virt    = (const float*)d_in[10];
    const int*   ei_s    = (const int*)d_in[11];
    const int*   ei_t    = (const int*)d_in[12];
    const int*   len_s   = (const int*)d_in[13];
    const int*   len_t   = (const int*)d_in[14];

    int Ns = in_sizes[0] / 32;
    int Nt = in_sizes[1] / 32;
    int Es = in_sizes[11] / 2;
    int Et = in_sizes[12] / 2;
    int Ntot = Ns + Nt;
    int Etot = Es + Et;

    // ---- workspace layout ----
    char* w = (char*)d_ws;
    int* off  = (int*)w;              w += 1024 * 4;
    int* bsum = (int*)w;              w += 256 * 4;
    int* rs   = (int*)w;              w += (size_t)Ntot * 4;
    int* cur  = (int*)w;              w += (size_t)Ntot * 4;
    int* src  = (int*)w;              w += (size_t)Etot * 4;
    w = (char*)(((size_t)w + 255) & ~(size_t)255);
    float* agg = (float*)w;           w += (size_t)Ntot * 64 * 4;  // gather out; later emb (in-place)
    float* h1  = (float*)w;           w += (size_t)Ntot * 64 * 4;

    float* out_gamma = (float*)d_out;
    float* out_cost  = out_gamma + (size_t)PAIRS * MAXN * MAXN;
    float* out_geds  = out_cost + (size_t)PAIRS * MAXN * MAXN;

    offsets_kernel<<<1, PAIRS, 0, stream>>>(len_s, len_t, off);

    // ---- combined CSR build ----
    hipMemsetAsync(rs, 0, (size_t)Ntot * 4, stream);
    count2_kernel<<<(Etot + 255) / 256, 256, 0, stream>>>(ei_s, ei_t, rs, Es, Et, Ns);
    int nb = (Ntot + 1023) / 1024;
    scan1_kernel<<<nb, 256, 0, stream>>>(rs, bsum, Ntot);
    scan2_kernel<<<1, 256, 0, stream>>>(bsum, nb);
    scan3_kernel<<<(Ntot + 255) / 256, 256, 0, stream>>>(rs, bsum, cur, Ntot);
    fill2_kernel<<<(Etot + 255) / 256, 256, 0, stream>>>(ei_s, ei_t, cur, src, Es, Et, Ns);

    int gblk = (Ntot + 63) / 64;

    // ---- combined GNN ----
    gather_kernel<32><<<(int)(((long long)Ntot * 8 + 255) / 256), 256, 0, stream>>>(
        x_s, x_t, Ns, rs, cur, src, agg, Ntot);
    lin_gemm_kernel<32><<<gblk, 256, 0, stream>>>(
        agg, x_s, x_t, Ns, W_rel0, b_rel0, W_root0, h1, Ntot);
    gather_kernel<64><<<(int)(((long long)Ntot * 16 + 255) / 256), 256, 0, stream>>>(
        h1, h1, Ns, rs, cur, src, agg, Ntot);
    // fused layer2 + emb: reads agg (own rows) + h1 + x, writes emb in-place into agg
    lin64_emb_kernel<<<gblk, 256, 0, stream>>>(
        agg, h1, x_s, x_t, Ns, W_rel1, b_rel1, W_root1, W_e, b_e, agg, Ntot);

    // ---- fused cost + sinkhorn ----
    fused_cost_sinkhorn_kernel<<<PAIRS, 512, 0, stream>>>(
        agg, agg + (size_t)Ns * 64, virt, len_s, len_t, off,
        out_cost, out_gamma, out_geds, Ns);
}